// Round 9
// baseline (874.633 us; speedup 1.0000x reference)
//
#include <hip/hip_runtime.h>
#include <hip/hip_bf16.h>
#include <stdint.h>

typedef __attribute__((ext_vector_type(8))) short bf16x8;
typedef __attribute__((ext_vector_type(4))) float f32x4;
typedef __attribute__((ext_vector_type(16))) float f32x16;
typedef __attribute__((ext_vector_type(4))) int int4v;

#define DEVI static __device__ __forceinline__

DEVI unsigned short f2b(float f) {
  union { float f; unsigned u; } v; v.f = f;
  unsigned r = (v.u + 0x7FFFu + ((v.u >> 16) & 1u)) >> 16;
  return (unsigned short)r;
}
DEVI float b2f(unsigned short h) {
  union { unsigned u; float f; } v; v.u = ((unsigned)h) << 16;
  return v.f;
}
DEVI unsigned encf(float f) {
  union { float f; unsigned u; } v; v.f = f;
  return (v.u & 0x80000000u) ? ~v.u : (v.u | 0x80000000u);
}
DEVI float decf(unsigned u) {
  union { unsigned u; float f; } v;
  v.u = (u & 0x80000000u) ? (u & 0x7FFFFFFFu) : ~u;
  return v.f;
}
DEVI void gload16(const void* g, void* l) {
  __builtin_amdgcn_global_load_lds(
      (const __attribute__((address_space(1))) unsigned int*)g,
      (__attribute__((address_space(3))) unsigned int*)l, 16, 0, 0);
}

// ---------------- weight reorder: dst[r][cib][tap][ci32] bf16 <- src[r][ci][tap] f32
__global__ __launch_bounds__(256) void k_reorder_w2(const float* __restrict__ src,
                                                    unsigned short* __restrict__ dst,
                                                    int CI) {
  int r = blockIdx.x;
  int t = threadIdx.x;
  const float* s = src + (size_t)r * CI * 9;
  unsigned short* d = dst + (size_t)r * CI * 9;
  for (int ci0 = 0; ci0 < CI; ci0 += 256) {
    int ci = ci0 + t;
    float v[9];
#pragma unroll
    for (int k = 0; k < 9; k++) v[k] = s[(size_t)ci * 9 + k];
    unsigned short* db = d + (size_t)(ci >> 5) * 288 + (ci & 31);
#pragma unroll
    for (int k = 0; k < 9; k++) db[(size_t)k * 32] = f2b(v[k]);
  }
}

// WgT[po][tap][ciw32][chunk32] f32 <- Wg[po][ci][tap]  (ci = chunk*32 + ciw)
__global__ void k_reorder_wg(const float* __restrict__ src, float* __restrict__ dst) {
  int idx = blockIdx.x * 256 + threadIdx.x;  // total 73728
  int ci = idx & 1023;
  int rt = idx >> 10;
  int tap = rt % 9;
  int po = rt / 9;
  dst[(((size_t)po * 9 + tap) * 32 + (ci & 31)) * 32 + (ci >> 5)] =
      src[((size_t)po * 1024 + ci) * 9 + tap];
}

// ---------------- zero the pad ring of an NHWC buffer (replaces big memsets)
__global__ void k_border(unsigned short* __restrict__ p, int H, int wpad, int C8,
                         int nImg) {
  int inner = H - 2 * wpad;
  int borderPx = H * H - inner * inner;
  long total = (long)borderPx * C8 * nImg;
  int topN = wpad * H;
  for (long i = (long)blockIdx.x * 256 + threadIdx.x; i < total;
       i += (long)gridDim.x * 256) {
    int c = (int)(i % C8);
    long r2 = i / C8;
    int px = (int)(r2 % borderPx);
    int img = (int)(r2 / borderPx);
    int y, x;
    if (px < topN) {
      y = px / H; x = px % H;
    } else if (px < 2 * topN) {
      int q = px - topN; y = H - 1 - (q / H); x = q % H;
    } else {
      int q = px - 2 * topN;
      int row = q / (2 * wpad), cc = q % (2 * wpad);
      y = wpad + row;
      x = cc < wpad ? cc : H - 2 * wpad + cc;
    }
    *(int4v*)&p[((((size_t)img * H + y) * H + x) * C8 + c) * 8] = int4v{0, 0, 0, 0};
  }
}

// ---------------- pad/transpose: x NCHW f32 -> NHWC bf16
__global__ __launch_bounds__(256) void k_pad(const float* __restrict__ xin,
                                             unsigned short* __restrict__ xf1,
                                             unsigned short* __restrict__ cp) {
  __shared__ unsigned short lds[64 * 66];
  int t = threadIdx.x;
  int y = blockIdx.x;   // 0..63
  int fb = blockIdx.y;  // 0..9 = f*2+b
  int f = fb >> 1, b = fb & 1;
  const float* src = xin + (size_t)fb * 512 * 4096 + y * 64;
  unsigned short* base;
  if (f == 2) {
    base = cp + (((size_t)b * 66) + y + 1) * 66 * 512 + 512;
  } else {
    int fi = f < 2 ? f : f - 1;
    base = xf1 + (((size_t)(fi * 2 + b) * 68) + y + 2) * 68 * 512 + 2 * 512;
  }
  for (int c0 = 0; c0 < 512; c0 += 64) {
#pragma unroll
    for (int r = 0; r < 16; ++r) {
      int ci = r * 4 + (t >> 6);
      int xx = t & 63;
      lds[ci * 66 + xx] = f2b(src[(size_t)(c0 + ci) * 4096 + xx]);
    }
    __syncthreads();
    int xp = t >> 2;
    int cc = (t & 3) * 16;
    __align__(16) unsigned short vals[16];
#pragma unroll
    for (int i = 0; i < 16; i++) vals[i] = lds[(cc + i) * 66 + xp];
    unsigned short* dst = base + (size_t)xp * 512 + c0 + cc;
    *(int4v*)(dst) = *(const int4v*)(vals);
    *(int4v*)(dst + 8) = *(const int4v*)(vals + 8);
    __syncthreads();
  }
}

// ---------------- correlation partials (f32, exact): corrpart[part][pair][b][25][64][64]
__global__ __launch_bounds__(256) void k_corr(const float* __restrict__ xin,
                                              float* __restrict__ corrpart) {
  __shared__ float f1h[2][20][21];
  int t = threadIdx.x;
  int tx = t & 15, ty = t >> 4;
  int x0 = blockIdx.x * 16, y0 = blockIdx.y * 16;
  int z = blockIdx.z;
  int b = z & 1, pair = (z >> 1) & 3, part = z >> 3;
  int s = pair < 2 ? pair : pair + 1;
  const float* f2 = xin + ((size_t)(2 * 2 + b) * 512) * 4096;
  const float* f1 = xin + ((size_t)(s * 2 + b) * 512) * 4096;
  float acc[25];
#pragma unroll
  for (int d = 0; d < 25; d++) acc[d] = 0.f;
  int y = y0 + ty, x = x0 + tx;
  for (int c = part * 128; c < part * 128 + 128; c += 2) {
    for (int k = t; k < 800; k += 256) {
      int ch = k / 400, e = k - ch * 400;
      int r = e / 20, ccx = e - r * 20;
      int gy = y0 + r - 2, gx = x0 + ccx - 2;
      float v = 0.f;
      if ((unsigned)gy < 64u && (unsigned)gx < 64u)
        v = f1[(size_t)(c + ch) * 4096 + gy * 64 + gx];
      f1h[ch][r][ccx] = v;
    }
    float f2a = f2[(size_t)c * 4096 + y * 64 + x];
    float f2c = f2[(size_t)(c + 1) * 4096 + y * 64 + x];
    __syncthreads();
#pragma unroll
    for (int d = 0; d < 25; ++d) {
      int di = d / 5, dj = d % 5;
      acc[d] += f2a * f1h[0][ty + di][tx + dj] + f2c * f1h[1][ty + di][tx + dj];
    }
    __syncthreads();
  }
  float* out = corrpart + ((size_t)((part * 4 + pair) * 2 + b) * 25) * 4096;
#pragma unroll
  for (int d = 0; d < 25; d++) out[(size_t)d * 4096 + y * 64 + x] = acc[d];
}

// ---------------- combine partials + global max per pair
__global__ __launch_bounds__(256) void k_corr_combine(const float* __restrict__ cpart,
                                                      float* __restrict__ corr,
                                                      unsigned* __restrict__ maxb) {
  const size_t PERPAIR = (size_t)2 * 25 * 4096;
  int pair = blockIdx.y;
  size_t i4 = ((size_t)blockIdx.x * 256 + threadIdx.x) * 4;
  f32x4 sacc = {0.f, 0.f, 0.f, 0.f};
#pragma unroll
  for (int p = 0; p < 4; p++)
    sacc += *(const f32x4*)(cpart + ((size_t)(p * 4 + pair)) * PERPAIR + i4);
  *(f32x4*)(corr + (size_t)pair * PERPAIR + i4) = sacc;
  float m = fmaxf(fmaxf(sacc[0], sacc[1]), fmaxf(sacc[2], sacc[3]));
#pragma unroll
  for (int off = 32; off; off >>= 1) m = fmaxf(m, __shfl_xor(m, off));
  __shared__ float wm[4];
  if ((threadIdx.x & 63) == 0) wm[threadIdx.x >> 6] = m;
  __syncthreads();
  if (threadIdx.x == 0) {
    float mm = fmaxf(fmaxf(wm[0], wm[1]), fmaxf(wm[2], wm[3]));
    atomicMax(maxb + pair, encf(mm));
  }
}

// ---------------- softmax + 5x5 gather from bf16 NHWC -> nfpad [pair][b][66][66][512]
__global__ __launch_bounds__(256) void k_attn3(const unsigned short* __restrict__ xf1,
                                               const float* __restrict__ corr,
                                               const unsigned* __restrict__ maxb,
                                               unsigned short* __restrict__ nfpad) {
  __shared__ unsigned short f1t[400 * 8];
  int t = threadIdx.x;
  int tx = t & 15, ty = t >> 4;
  int x0 = blockIdx.x * 16, y0 = blockIdx.y * 16;
  int z = blockIdx.z;
  int b = z & 1, pair = (z >> 1) & 3, cgh = z >> 3;
  const unsigned short* f1 = xf1 + ((size_t)(pair * 2 + b)) * 68 * 68 * 512;
  int y = y0 + ty, x = x0 + tx;
  const float* cr = corr + ((size_t)(pair * 2 + b)) * 25 * 4096 + y * 64 + x;
  float p[25];
  float mx = -1e30f;
#pragma unroll
  for (int d = 0; d < 25; d++) {
    p[d] = cr[(size_t)d * 4096];
    mx = fmaxf(mx, p[d]);
  }
  float gs = 20.f / decf(maxb[pair]);
  float ss = 0.f;
#pragma unroll
  for (int d = 0; d < 25; d++) {
    p[d] = __expf((p[d] - mx) * gs);
    ss += p[d];
  }
  float inv = 1.f / ss;
#pragma unroll
  for (int d = 0; d < 25; d++) p[d] *= inv;

  for (int q = 0; q < 4; ++q) {
    int cg = cgh * 4 + q;
    for (int k = t; k < 400; k += 256) {
      int r = k / 20, c = k - r * 20;
      *(int4v*)&f1t[k * 8] =
          *(const int4v*)&f1[((size_t)(y0 + r) * 68 + (x0 + c)) * 512 + cg * 8];
    }
    __syncthreads();
    float acc[8] = {0.f, 0.f, 0.f, 0.f, 0.f, 0.f, 0.f, 0.f};
#pragma unroll
    for (int d = 0; d < 25; d++) {
      bf16x8 v = *(const bf16x8*)&f1t[((ty + d / 5) * 20 + tx + d % 5) * 8];
      float pd = p[d];
#pragma unroll
      for (int e = 0; e < 8; e++) acc[e] += pd * b2f((unsigned short)v[e]);
    }
    __align__(16) unsigned short o[8];
#pragma unroll
    for (int e = 0; e < 8; e++) o[e] = f2b(acc[e]);
    *(int4v*)&nfpad[(((size_t)(pair * 2 + b) * 66 + (y + 1)) * 66 + (x + 1)) * 512 +
                    cg * 8] = *(const int4v*)o;
    __syncthreads();
  }
}

// ---------------- gate conv, coalesced weight reads via [po][tap][ciw][chunk] layout
__global__ __launch_bounds__(256) void k_gate3(const unsigned short* __restrict__ cp,
                                               const unsigned short* __restrict__ nfp,
                                               const float* __restrict__ wgt,
                                               const float* __restrict__ bg,
                                               float* __restrict__ gw) {
  int t = threadIdx.x;
  int z = blockIdx.z;
  int b = z & 1, pair = z >> 1;
  int y = blockIdx.y;
  int x = blockIdx.x * 8 + (t >> 5);
  int chunk = t & 31;
  int ci0 = chunk * 32;
  int half = ci0 >> 9;
  int ch0 = ci0 & 511;
  const unsigned short* src = half ? (nfp + ((size_t)(pair * 2 + b)) * 66 * 66 * 512)
                                   : (cp + ((size_t)b) * 66 * 66 * 512);
  const float* w0b = wgt + ((size_t)(pair * 2 + 0) * 9) * 1024;
  const float* w1b = wgt + ((size_t)(pair * 2 + 1) * 9) * 1024;
  float a0 = 0.f, a1 = 0.f;
  for (int tap = 0; tap < 9; ++tap) {
    int ky = tap / 3, kx = tap % 3;
    const unsigned short* ip = src + ((size_t)(y + ky) * 66 + (x + kx)) * 512 + ch0;
    const float* w0 = w0b + tap * 1024 + chunk;
    const float* w1 = w1b + tap * 1024 + chunk;
#pragma unroll
    for (int q = 0; q < 4; ++q) {
      bf16x8 v8 = *(const bf16x8*)(ip + q * 8);
#pragma unroll
      for (int e = 0; e < 8; e++) {
        float f = b2f((unsigned short)v8[e]);
        a0 += f * w0[(q * 8 + e) * 32];
        a1 += f * w1[(q * 8 + e) * 32];
      }
    }
  }
#pragma unroll
  for (int md = 1; md < 32; md <<= 1) {
    a0 += __shfl_xor(a0, md);
    a1 += __shfl_xor(a1, md);
  }
  if ((t & 31) == 0) {
    float g0 = 1.f / (1.f + __expf(-(a0 + bg[pair * 2 + 0])));
    float g1 = 1.f / (1.f + __expf(-(a1 + bg[pair * 2 + 1])));
    gw[(((size_t)(pair * 2 + b) * 2 + 0) * 64 + y) * 64 + x] = g0;
    gw[(((size_t)(pair * 2 + b) * 2 + 1) * 64 + y) * 64 + x] = g1;
  }
}

// ---------------- fg = [center*g0, nf*g1] -> fgp[pz][2][66][66][1024] bf16
__global__ __launch_bounds__(256) void k_fg(const unsigned short* __restrict__ cp,
                                            const unsigned short* __restrict__ nfp,
                                            const float* __restrict__ gw,
                                            unsigned short* __restrict__ fgp, int pairBase) {
  int pz = blockIdx.y;
  int pair = pairBase + pz;
  unsigned short* dstBase = fgp + (size_t)pz * 2 * 66 * 66 * 1024;
  size_t idx = (size_t)blockIdx.x * 256 + threadIdx.x;
  int chunk = (int)(idx & 127);
  size_t px = idx >> 7;
  int b = (int)(px >> 12), rem = (int)(px & 4095);
  int y = rem >> 6, x = rem & 63;
  int ci0 = chunk * 8;
  int half = ci0 >> 9;
  float g = gw[(((size_t)(pair * 2 + b) * 2 + half) * 64 + y) * 64 + x];
  const unsigned short* src = half ? (nfp + ((size_t)(pair * 2 + b)) * 66 * 66 * 512)
                                   : (cp + (size_t)b * 66 * 66 * 512);
  size_t poff = ((size_t)(y + 1) * 66 + (x + 1)) * 512 + (ci0 - half * 512);
  bf16x8 v = *(const bf16x8*)(src + poff);
  __align__(16) unsigned short o[8];
#pragma unroll
  for (int e = 0; e < 8; e++) o[e] = f2b(b2f((unsigned short)v[e]) * g);
  *(int4v*)(dstBase + ((size_t)(b * 66 + y + 1) * 66 + (x + 1)) * 1024 + ci0) =
      *(const int4v*)o;
}

// ---------------- 256x256x64 phase-templated implicit-GEMM conv, 32x32x16 MFMA
// Same verified phase/hazard schedule as r8's conv5 (stage A@P2, B@P3, vmcnt(8)),
// but: mfma_f32_32x32x16_bf16 (32 MFMA/wave/K-tile instead of 64; +15% ceiling),
// and wave-uniform (SALU) tap addressing in stB. Wave tile 128x64 = 4 rowtiles x
// 2 coltiles of 32x32; acc[4][2] f32x16. A/B frag: row=l&31, k=(l>>5)*8+e;
// C/D: col=lane&31, row=(reg&3)+8*(reg>>2)+4*(lane>>5)  [m74/m101].
// MODE 0: Wd (+bias+relu, bf16 out). MODE 2: Wc split-K/4, bf16 partials.
template <int CI, int MODE>
__global__ __launch_bounds__(512) void conv6(const unsigned short* __restrict__ inB,
                                             const unsigned short* __restrict__ WTb,
                                             const float* __restrict__ bias,
                                             unsigned short* __restrict__ outB,
                                             unsigned short* __restrict__ outP,
                                             int pairOfs, int multiz) {
  constexpr int K = 9 * CI;
  constexpr int KTOT = K / 64;                       // 144 (Wd) / 288 (Wc)
  constexpr int KT = (MODE == 2) ? KTOT / 4 : KTOT;  // 144 / 72
  __shared__ unsigned short As[2 * 2 * 8192];
  __shared__ unsigned short Bs[2 * 2 * 8192];

  int t = threadIdx.x;
  int bid = blockIdx.x;
  int xcd = bid & 7;
  int z, m, n;
  if (multiz) {
    z = xcd >> 1; m = xcd & 1; n = bid >> 3;
  } else {
    z = 0; m = bid & 1; n = bid >> 1;
  }
  const unsigned short* inPad = (MODE == 0) ? inB + (size_t)z * 2 * 66 * 66 * 1024 : inB;
  const unsigned short* WT = (MODE == 0) ? WTb + (size_t)z * 512 * 9216 : WTb;
  const int kt0 = (MODE == 2) ? z * KT : 0;
  const int ktEnd = kt0 + KT;
  int co0 = m * 256, n0 = n * 256;

  // staging geometry: idx2 = rr*512+t in [0,1024): row=idx2>>3 (0..127), destchunk=idx2&7
  // source k-chunk kc = destchunk ^ (row&7); dest linear (gload_lds requirement)
  int rowS[2], kcS[2], linS[2];
  size_t bpix2[2][2];  // [h][rr]: pixel base + (kc&3)*8 pre-added
#pragma unroll
  for (int rr = 0; rr < 2; rr++) {
    int idx2 = rr * 512 + t;
    rowS[rr] = idx2 >> 3;
    kcS[rr] = (idx2 & 7) ^ (rowS[rr] & 7);
    linS[rr] = idx2 * 8;
#pragma unroll
    for (int h = 0; h < 2; h++) {
      int ng = n0 + h * 128 + rowS[rr];
      int bb = ng >> 12, yy = (ng >> 6) & 63, xx = ng & 63;
      bpix2[h][rr] = (size_t)((bb * 66 + yy) * 66 + xx) * CI + (kcS[rr] & 3) * 8;
    }
  }

  f32x16 acc[4][2];
#pragma unroll
  for (int i = 0; i < 4; i++)
#pragma unroll
    for (int j = 0; j < 2; j++)
#pragma unroll
      for (int e = 0; e < 16; e++) acc[i][j][e] = 0.f;

  int wid = t >> 6, l = t & 63;
  int wm = wid >> 2, wn = wid & 3;
  int l32 = l & 31, lhi = l >> 5, l7 = l & 7;

  auto stA = [&](int bufp, int h, int kt) {
#pragma unroll
    for (int rr = 0; rr < 2; rr++)
      gload16(WT + (size_t)(co0 + h * 128 + rowS[rr]) * K + kt * 64 + kcS[rr] * 8,
              &As[(bufp * 2 + h) * 8192 + linS[rr]]);
  };
  auto stB = [&](int bufp, int h, int kt) {
    // wave-uniform tap decode (kt uniform -> SALU); per-thread only a select
    int g0 = kt * 2, g1 = g0 + 1;
    int cib0 = g0 / 9, tap0 = g0 - cib0 * 9;
    int cib1 = g1 / 9, tap1 = g1 - cib1 * 9;
    int off0 = ((tap0 / 3) * 66 + tap0 % 3) * CI + cib0 * 32;
    int off1 = ((tap1 / 3) * 66 + tap1 % 3) * CI + cib1 * 32;
#pragma unroll
    for (int rr = 0; rr < 2; rr++)
      gload16(inPad + bpix2[h][rr] + ((kcS[rr] & 4) ? off1 : off0),
              &Bs[(bufp * 2 + h) * 8192 + linS[rr]]);
  };

  // frags: afr0 = rowtiles 0-1, afr1 = rowtiles 2-3 (within wave's 128-row half);
  // bfr0 = coltile 0, bfr1 = coltile 1 (32 cols each). [rt2][ks] / [ks].
  bf16x8 afr0[2][4], afr1[2][4], bfr0[4], bfr1[4];

#define RDA32(DST, C, MH)                                                       \
  _Pragma("unroll") for (int rt2 = 0; rt2 < 2; ++rt2) {                         \
    int row = ((MH)*2 + rt2) * 32 + l32;                                        \
    _Pragma("unroll") for (int ks = 0; ks < 4; ++ks) {                          \
      int pos = (ks * 2 + lhi) ^ l7;                                            \
      DST[rt2][ks] = *(const bf16x8*)&As[((C)*2 + wm) * 8192 + row * 64 + pos * 8]; \
    }                                                                           \
  }
#define RDB32(DST, C, NH)                                                       \
  _Pragma("unroll") for (int ks = 0; ks < 4; ++ks) {                            \
    int row = (wn & 1) * 64 + (NH)*32 + l32;                                    \
    int pos = (ks * 2 + lhi) ^ l7;                                              \
    DST[ks] =                                                                   \
        *(const bf16x8*)&Bs[((C)*2 + (wn >> 1)) * 8192 + row * 64 + pos * 8];   \
  }
#define QUAD32(AF, BF, MH, NH)                                                  \
  __builtin_amdgcn_s_setprio(1);                                                \
  _Pragma("unroll") for (int ks = 0; ks < 4; ++ks) {                            \
    _Pragma("unroll") for (int rt2 = 0; rt2 < 2; ++rt2) {                       \
      acc[(MH)*2 + rt2][NH] = __builtin_amdgcn_mfma_f32_32x32x16_bf16(          \
          AF[rt2][ks], BF[ks], acc[(MH)*2 + rt2][NH], 0, 0, 0);                 \
    }                                                                           \
  }                                                                             \
  __builtin_amdgcn_s_setprio(0);
#define LGKM0_FENCE                                        \
  asm volatile("s_waitcnt lgkmcnt(0)" ::: "memory");       \
  __builtin_amdgcn_sched_barrier(0);

  // prologue: stage kt0 -> buf0, kt0+1 -> buf1 (8+8 loads); wait kt0, barrier
  {
    int b0 = kt0 & 1, b1 = b0 ^ 1;
    stA(b0, 0, kt0); stA(b0, 1, kt0); stB(b0, 0, kt0); stB(b0, 1, kt0);
    stA(b1, 0, kt0 + 1); stA(b1, 1, kt0 + 1); stB(b1, 0, kt0 + 1); stB(b1, 1, kt0 + 1);
    asm volatile("s_waitcnt vmcnt(8)" ::: "memory");
    __builtin_amdgcn_s_barrier();
  }

  for (int kt = kt0; kt < ktEnd; ++kt) {
    int cur = kt & 1;
    const bool pf = (kt + 2 < ktEnd);
    // P0: read A rowtiles 0-1 + B coltile 0; no staging
    RDA32(afr0, cur, 0);
    RDB32(bfr0, cur, 0);
    __builtin_amdgcn_s_barrier();
    LGKM0_FENCE
    QUAD32(afr0, bfr0, 0, 0)
    __builtin_amdgcn_s_barrier();
    // P1: read A rowtiles 2-3; no staging (A slots live until these reads done)
    RDA32(afr1, cur, 1);
    __builtin_amdgcn_s_barrier();
    LGKM0_FENCE
    QUAD32(afr1, bfr0, 1, 0)
    __builtin_amdgcn_s_barrier();
    // P2: read B coltile 1; A fully consumed (P0+P1) -> stage both A halves of kt+2
    RDB32(bfr1, cur, 1);
    if (pf) { stA(cur, 0, kt + 2); stA(cur, 1, kt + 2); }
    __builtin_amdgcn_s_barrier();
    LGKM0_FENCE
    QUAD32(afr1, bfr1, 1, 1)
    __builtin_amdgcn_s_barrier();
    // P3: B fully consumed (P0+P2) -> stage both B halves of kt+2
    if (pf) { stB(cur, 0, kt + 2); stB(cur, 1, kt + 2); }
    __builtin_amdgcn_sched_barrier(0);
    QUAD32(afr0, bfr1, 0, 1)
    if (pf) {
      asm volatile("s_waitcnt vmcnt(8)" ::: "memory");  // kt+1's 8 loads retired
    } else {
      asm volatile("s_waitcnt vmcnt(0)" ::: "memory");
    }
    __builtin_amdgcn_s_barrier();
  }
#undef RDA32
#undef RDB32
#undef QUAD32
#undef LGKM0_FENCE

  // epilogue: C/D layout col=lane&31, row=(r&3)+8*(r>>2)+4*(lane>>5)
#pragma unroll
  for (int rt = 0; rt < 4; rt++) {
#pragma unroll
    for (int ct = 0; ct < 2; ct++) {
      int colg = n0 + wn * 64 + ct * 32 + l32;
      int bb = colg >> 12, yy = (colg >> 6) & 63, xx = colg & 63;
#pragma unroll
      for (int r = 0; r < 16; r++) {
        int row = wm * 128 + rt * 32 + (r & 3) + 8 * (r >> 2) + 4 * lhi;
        int co = co0 + row;
        if (MODE == 0) {
          int zc = (z + pairOfs) * 512 + co;
          float v = acc[rt][ct][r] + bias[zc];
          v = v > 0.f ? v : 0.f;
          outB[((size_t)(bb * 66 + yy + 1) * 66 + (xx + 1)) * 2048 + zc] = f2b(v);
        } else {
          outP[((size_t)(z * 512 + co) << 13) + colg] = f2b(acc[rt][ct][r]);
        }
      }
    }
  }
}

// ---------------- combine split-K bf16 partials: out = relu(sum + bias), f32 NCHW
__global__ __launch_bounds__(256) void k_combine2(const unsigned short* __restrict__ p,
                                                  const float* __restrict__ bc,
                                                  float* __restrict__ out) {
  size_t i8 = ((size_t)blockIdx.x * 256 + threadIdx.x) * 8;  // over 512*8192
  int co = (int)(i8 >> 13);
  int ng = (int)(i8 & 8191);
  float s[8] = {0.f, 0.f, 0.f, 0.f, 0.f, 0.f, 0.f, 0.f};
#pragma unroll
  for (int zz = 0; zz < 4; zz++) {
    bf16x8 v = *(const bf16x8*)&p[((size_t)(zz * 512 + co) << 13) + ng];
#pragma unroll
    for (int e = 0; e < 8; e++) s[e] += b2f((unsigned short)v[e]);
  }
  float bb = bc[co];
  int batch = ng >> 12, rem = ng & 4095;
  float* o = out + (((size_t)(batch * 512 + co)) << 12) + rem;
#pragma unroll
  for (int e = 0; e < 8; e++) {
    float q = s[e] + bb;
    o[e] = q > 0.f ? q : 0.f;
  }
}

extern "C" void kernel_launch(void* const* d_in, const int* in_sizes, int n_in,
                              void* d_out, int out_size, void* d_ws, size_t ws_size,
                              hipStream_t stream) {
  const float* x = (const float*)d_in[0];
  const float* Wg = (const float*)d_in[1];
  const float* bg = (const float*)d_in[2];
  const float* Wd = (const float*)d_in[3];
  const float* bd = (const float*)d_in[4];
  const float* Wc = (const float*)d_in[5];
  const float* bc = (const float*)d_in[6];
  float* out = (float*)d_out;

  char* ws = (char*)d_ws;
  size_t off = 0;
  auto alloc = [&](size_t bytes) {
    void* p = ws + off;
    off = (off + bytes + 255) & ~(size_t)255;
    return p;
  };
  const size_t SZ_WDT = (size_t)2048 * 9216 * 2;
  const size_t SZ_WCT = (size_t)512 * 18432 * 2;
  const size_t SZ_WGT = (size_t)4 * 2 * 9 * 1024 * 4;
  const size_t SZ_CP = (size_t)2 * 66 * 66 * 512 * 2;
  const size_t SZ_NF = (size_t)4 * 2 * 66 * 66 * 512 * 2;
  const size_t SZ_GT = (size_t)2 * 66 * 66 * 2048 * 2;
  const size_t SZ_GW = (size_t)4 * 2 * 2 * 4096 * 4;
  const size_t SZ_XF1 = (size_t)4 * 2 * 68 * 68 * 512 * 2;
  const size_t SZ_CORR = (size_t)4 * 2 * 25 * 4096 * 4;
  const size_t SZ_FG1 = (size_t)2 * 66 * 66 * 1024 * 2;
  const size_t SZ_FG4 = SZ_FG1 * 4;

  unsigned short* WdT = (unsigned short*)alloc(SZ_WDT);
  unsigned short* WcT = (unsigned short*)alloc(SZ_WCT);
  float* WgT = (float*)alloc(SZ_WGT);
  unsigned short* centerpad = (unsigned short*)alloc(SZ_CP);
  unsigned short* nfpad = (unsigned short*)alloc(SZ_NF);
  unsigned short* gatedpad = (unsigned short*)alloc(SZ_GT);
  float* gw = (float*)alloc(SZ_GW);
  unsigned* maxb = (unsigned*)alloc(256);

  // union region: phase1 {xf1, corr, cpart} -> phase2 {fg} -> phase3 {wcp}
  size_t unionOff = off;
  unsigned short* xf1 = (unsigned short*)(ws + unionOff);
  size_t o2 = unionOff + ((SZ_XF1 + 255) & ~(size_t)255);
  float* corr = (float*)(ws + o2);
  float* cpart = (float*)(ws + o2 + ((SZ_CORR + 255) & ~(size_t)255));
  unsigned short* fg = (unsigned short*)(ws + unionOff);
  unsigned short* wcp = (unsigned short*)(ws + unionOff);
  bool batched = ws_size >= unionOff + SZ_FG4;

  hipMemsetAsync(maxb, 0, 64, stream);

  // zero pad rings of buffers NOT aliased with the live union region
  k_border<<<512, 256, 0, stream>>>(xf1, 68, 2, 64, 8);
  k_border<<<512, 256, 0, stream>>>(centerpad, 66, 1, 64, 2);
  k_border<<<512, 256, 0, stream>>>(nfpad, 66, 1, 64, 8);
  k_border<<<512, 256, 0, stream>>>(gatedpad, 66, 1, 256, 2);

  k_reorder_w2<<<2048, 256, 0, stream>>>(Wd, WdT, 1024);
  k_reorder_w2<<<512, 256, 0, stream>>>(Wc, WcT, 2048);
  k_reorder_wg<<<288, 256, 0, stream>>>(Wg, WgT);
  k_pad<<<dim3(64, 10), 256, 0, stream>>>(x, xf1, centerpad);
  k_corr<<<dim3(4, 4, 32), 256, 0, stream>>>(x, cpart);
  k_corr_combine<<<dim3(200, 4), 256, 0, stream>>>(cpart, corr, maxb);
  k_attn3<<<dim3(4, 4, 128), 256, 0, stream>>>(xf1, corr, maxb, nfpad);
  k_gate3<<<dim3(8, 64, 8), 256, 0, stream>>>(centerpad, nfpad, WgT, bg, gw);

  // xf1/corr/cpart are dead NOW -> safe to zero fg's pad ring (fg aliases them)
  k_border<<<512, 256, 0, stream>>>(fg, 66, 1, 128, batched ? 8 : 2);

  if (batched) {
    k_fg<<<dim3(4096, 4), 256, 0, stream>>>(centerpad, nfpad, gw, fg, 0);
    conv6<1024, 0><<<256, 512, 0, stream>>>(fg, WdT, bd, gatedpad, nullptr, 0, 1);
  } else {
    for (int pair = 0; pair < 4; ++pair) {
      k_fg<<<dim3(4096, 1), 256, 0, stream>>>(centerpad, nfpad, gw, fg, pair);
      conv6<1024, 0><<<64, 512, 0, stream>>>(
          fg, WdT + (size_t)pair * 512 * 9216, bd, gatedpad, nullptr, pair, 0);
    }
  }
  conv6<2048, 2><<<256, 512, 0, stream>>>(gatedpad, WcT, nullptr, nullptr, wcp, 0, 1);
  k_combine2<<<2048, 256, 0, stream>>>(wcp, bc, out);
}

// Round 10
// 823.622 us; speedup vs baseline: 1.0619x; 1.0619x over previous
//
#include <hip/hip_runtime.h>
#include <hip/hip_bf16.h>
#include <stdint.h>

typedef __attribute__((ext_vector_type(8))) short bf16x8;
typedef __attribute__((ext_vector_type(4))) float f32x4;
typedef __attribute__((ext_vector_type(4))) int int4v;

#define DEVI static __device__ __forceinline__

DEVI unsigned short f2b(float f) {
  union { float f; unsigned u; } v; v.f = f;
  unsigned r = (v.u + 0x7FFFu + ((v.u >> 16) & 1u)) >> 16;
  return (unsigned short)r;
}
DEVI float b2f(unsigned short h) {
  union { unsigned u; float f; } v; v.u = ((unsigned)h) << 16;
  return v.f;
}
DEVI unsigned encf(float f) {
  union { float f; unsigned u; } v; v.f = f;
  return (v.u & 0x80000000u) ? ~v.u : (v.u | 0x80000000u);
}
DEVI float decf(unsigned u) {
  union { unsigned u; float f; } v;
  v.u = (u & 0x80000000u) ? (u & 0x7FFFFFFFu) : ~u;
  return v.f;
}
DEVI void gload16(const void* g, void* l) {
  __builtin_amdgcn_global_load_lds(
      (const __attribute__((address_space(1))) unsigned int*)g,
      (__attribute__((address_space(3))) unsigned int*)l, 16, 0, 0);
}

// ---------------- weight reorder: dst[r][cib][tap][ci32] bf16 <- src[r][ci][tap] f32
__global__ __launch_bounds__(256) void k_reorder_w2(const float* __restrict__ src,
                                                    unsigned short* __restrict__ dst,
                                                    int CI) {
  int r = blockIdx.x;
  int t = threadIdx.x;
  const float* s = src + (size_t)r * CI * 9;
  unsigned short* d = dst + (size_t)r * CI * 9;
  for (int ci0 = 0; ci0 < CI; ci0 += 256) {
    int ci = ci0 + t;
    float v[9];
#pragma unroll
    for (int k = 0; k < 9; k++) v[k] = s[(size_t)ci * 9 + k];
    unsigned short* db = d + (size_t)(ci >> 5) * 288 + (ci & 31);
#pragma unroll
    for (int k = 0; k < 9; k++) db[(size_t)k * 32] = f2b(v[k]);
  }
}

// WgT[po][tap][ciw32][chunk32] f32 <- Wg[po][ci][tap]  (ci = chunk*32 + ciw)
__global__ void k_reorder_wg(const float* __restrict__ src, float* __restrict__ dst) {
  int idx = blockIdx.x * 256 + threadIdx.x;  // total 73728
  int ci = idx & 1023;
  int rt = idx >> 10;
  int tap = rt % 9;
  int po = rt / 9;
  dst[(((size_t)po * 9 + tap) * 32 + (ci & 31)) * 32 + (ci >> 5)] =
      src[((size_t)po * 1024 + ci) * 9 + tap];
}

// ---------------- zero the pad ring of an NHWC buffer (replaces big memsets)
__global__ void k_border(unsigned short* __restrict__ p, int H, int wpad, int C8,
                         int nImg) {
  int inner = H - 2 * wpad;
  int borderPx = H * H - inner * inner;
  long total = (long)borderPx * C8 * nImg;
  int topN = wpad * H;
  for (long i = (long)blockIdx.x * 256 + threadIdx.x; i < total;
       i += (long)gridDim.x * 256) {
    int c = (int)(i % C8);
    long r2 = i / C8;
    int px = (int)(r2 % borderPx);
    int img = (int)(r2 / borderPx);
    int y, x;
    if (px < topN) {
      y = px / H; x = px % H;
    } else if (px < 2 * topN) {
      int q = px - topN; y = H - 1 - (q / H); x = q % H;
    } else {
      int q = px - 2 * topN;
      int row = q / (2 * wpad), cc = q % (2 * wpad);
      y = wpad + row;
      x = cc < wpad ? cc : H - 2 * wpad + cc;
    }
    *(int4v*)&p[((((size_t)img * H + y) * H + x) * C8 + c) * 8] = int4v{0, 0, 0, 0};
  }
}

// ---------------- pad/transpose: x NCHW f32 -> NHWC bf16
__global__ __launch_bounds__(256) void k_pad(const float* __restrict__ xin,
                                             unsigned short* __restrict__ xf1,
                                             unsigned short* __restrict__ cp) {
  __shared__ unsigned short lds[64 * 66];
  int t = threadIdx.x;
  int y = blockIdx.x;   // 0..63
  int fb = blockIdx.y;  // 0..9 = f*2+b
  int f = fb >> 1, b = fb & 1;
  const float* src = xin + (size_t)fb * 512 * 4096 + y * 64;
  unsigned short* base;
  if (f == 2) {
    base = cp + (((size_t)b * 66) + y + 1) * 66 * 512 + 512;
  } else {
    int fi = f < 2 ? f : f - 1;
    base = xf1 + (((size_t)(fi * 2 + b) * 68) + y + 2) * 68 * 512 + 2 * 512;
  }
  for (int c0 = 0; c0 < 512; c0 += 64) {
#pragma unroll
    for (int r = 0; r < 16; ++r) {
      int ci = r * 4 + (t >> 6);
      int xx = t & 63;
      lds[ci * 66 + xx] = f2b(src[(size_t)(c0 + ci) * 4096 + xx]);
    }
    __syncthreads();
    int xp = t >> 2;
    int cc = (t & 3) * 16;
    __align__(16) unsigned short vals[16];
#pragma unroll
    for (int i = 0; i < 16; i++) vals[i] = lds[(cc + i) * 66 + xp];
    unsigned short* dst = base + (size_t)xp * 512 + c0 + cc;
    *(int4v*)(dst) = *(const int4v*)(vals);
    *(int4v*)(dst + 8) = *(const int4v*)(vals + 8);
    __syncthreads();
  }
}

// ---------------- correlation partials (f32): corrpart[part][pair][b][25][64][64]
// staging indices (div/mod + bounds) hoisted out of the channel loop
__global__ __launch_bounds__(256) void k_corr(const float* __restrict__ xin,
                                              float* __restrict__ corrpart) {
  __shared__ float f1h[840];  // [2][20][21]
  int t = threadIdx.x;
  int tx = t & 15, ty = t >> 4;
  int x0 = blockIdx.x * 16, y0 = blockIdx.y * 16;
  int z = blockIdx.z;
  int b = z & 1, pair = (z >> 1) & 3, part = z >> 3;
  int s = pair < 2 ? pair : pair + 1;
  const float* f2 = xin + ((size_t)(2 * 2 + b) * 512) * 4096;
  const float* f1 = xin + ((size_t)(s * 2 + b) * 512) * 4096;

  int cnt = (t < 32) ? 4 : 3;
  int ldso[4], goff[4], chv[4];
  bool val[4];
#pragma unroll
  for (int q = 0; q < 4; q++) {
    int k = t + q * 256;
    if (k >= 800) k = 799;  // dummy (masked by cnt)
    int ch = k >= 400;
    int e = k - ch * 400;
    int r = e / 20, cc = e - r * 20;
    int gy = y0 + r - 2, gx = x0 + cc - 2;
    val[q] = ((unsigned)gy < 64u) && ((unsigned)gx < 64u);
    ldso[q] = ch * 420 + r * 21 + cc;
    goff[q] = gy * 64 + gx;
    chv[q] = ch;
  }

  float acc[25];
#pragma unroll
  for (int d = 0; d < 25; d++) acc[d] = 0.f;
  int y = y0 + ty, x = x0 + tx;
  for (int c = part * 128; c < part * 128 + 128; c += 2) {
#pragma unroll
    for (int q = 0; q < 4; q++) {
      if (q < cnt) {
        float v = 0.f;
        if (val[q]) v = f1[(size_t)(c + chv[q]) * 4096 + goff[q]];
        f1h[ldso[q]] = v;
      }
    }
    float f2a = f2[(size_t)c * 4096 + y * 64 + x];
    float f2c = f2[(size_t)(c + 1) * 4096 + y * 64 + x];
    __syncthreads();
#pragma unroll
    for (int d = 0; d < 25; ++d) {
      int di = d / 5, dj = d % 5;
      acc[d] += f2a * f1h[(ty + di) * 21 + tx + dj] +
                f2c * f1h[420 + (ty + di) * 21 + tx + dj];
    }
    __syncthreads();
  }
  float* out = corrpart + ((size_t)((part * 4 + pair) * 2 + b) * 25) * 4096;
#pragma unroll
  for (int d = 0; d < 25; d++) out[(size_t)d * 4096 + y * 64 + x] = acc[d];
}

// ---------------- combine partials + global max per pair
__global__ __launch_bounds__(256) void k_corr_combine(const float* __restrict__ cpart,
                                                      float* __restrict__ corr,
                                                      unsigned* __restrict__ maxb) {
  const size_t PERPAIR = (size_t)2 * 25 * 4096;
  int pair = blockIdx.y;
  size_t i4 = ((size_t)blockIdx.x * 256 + threadIdx.x) * 4;
  f32x4 sacc = {0.f, 0.f, 0.f, 0.f};
#pragma unroll
  for (int p = 0; p < 4; p++)
    sacc += *(const f32x4*)(cpart + ((size_t)(p * 4 + pair)) * PERPAIR + i4);
  *(f32x4*)(corr + (size_t)pair * PERPAIR + i4) = sacc;
  float m = fmaxf(fmaxf(sacc[0], sacc[1]), fmaxf(sacc[2], sacc[3]));
#pragma unroll
  for (int off = 32; off; off >>= 1) m = fmaxf(m, __shfl_xor(m, off));
  __shared__ float wm[4];
  if ((threadIdx.x & 63) == 0) wm[threadIdx.x >> 6] = m;
  __syncthreads();
  if (threadIdx.x == 0) {
    float mm = fmaxf(fmaxf(wm[0], wm[1]), fmaxf(wm[2], wm[3]));
    atomicMax(maxb + pair, encf(mm));
  }
}

// ---------------- softmax + 5x5 gather from bf16 NHWC -> nfpad [pair][b][66][66][512]
// staging index decomposition hoisted out of the cg loop
__global__ __launch_bounds__(256) void k_attn3(const unsigned short* __restrict__ xf1,
                                               const float* __restrict__ corr,
                                               const unsigned* __restrict__ maxb,
                                               unsigned short* __restrict__ nfpad) {
  __shared__ unsigned short f1t[400 * 8];
  int t = threadIdx.x;
  int tx = t & 15, ty = t >> 4;
  int x0 = blockIdx.x * 16, y0 = blockIdx.y * 16;
  int z = blockIdx.z;
  int b = z & 1, pair = (z >> 1) & 3, cgh = z >> 3;
  const unsigned short* f1 = xf1 + ((size_t)(pair * 2 + b)) * 68 * 68 * 512;
  int y = y0 + ty, x = x0 + tx;
  const float* cr = corr + ((size_t)(pair * 2 + b)) * 25 * 4096 + y * 64 + x;

  // hoisted staging decomposition: k0 = t (always), k1 = t+256 (if t<144)
  int r0 = t / 20, c0 = t - r0 * 20;
  size_t go0 = ((size_t)(y0 + r0) * 68 + (x0 + c0)) * 512;
  bool has1 = t < 144;
  int k1 = t + 256;
  int r1 = k1 / 20, c1 = k1 - r1 * 20;
  size_t go1 = ((size_t)(y0 + r1) * 68 + (x0 + c1)) * 512;

  float p[25];
  float mx = -1e30f;
#pragma unroll
  for (int d = 0; d < 25; d++) {
    p[d] = cr[(size_t)d * 4096];
    mx = fmaxf(mx, p[d]);
  }
  float gs = 20.f / decf(maxb[pair]);
  float ss = 0.f;
#pragma unroll
  for (int d = 0; d < 25; d++) {
    p[d] = __expf((p[d] - mx) * gs);
    ss += p[d];
  }
  float inv = 1.f / ss;
#pragma unroll
  for (int d = 0; d < 25; d++) p[d] *= inv;

  for (int q = 0; q < 4; ++q) {
    int cg = cgh * 4 + q;
    *(int4v*)&f1t[t * 8] = *(const int4v*)&f1[go0 + cg * 8];
    if (has1) *(int4v*)&f1t[k1 * 8] = *(const int4v*)&f1[go1 + cg * 8];
    __syncthreads();
    float acc[8] = {0.f, 0.f, 0.f, 0.f, 0.f, 0.f, 0.f, 0.f};
#pragma unroll
    for (int d = 0; d < 25; d++) {
      bf16x8 v = *(const bf16x8*)&f1t[((ty + d / 5) * 20 + tx + d % 5) * 8];
      float pd = p[d];
#pragma unroll
      for (int e = 0; e < 8; e++) acc[e] += pd * b2f((unsigned short)v[e]);
    }
    __align__(16) unsigned short o[8];
#pragma unroll
    for (int e = 0; e < 8; e++) o[e] = f2b(acc[e]);
    *(int4v*)&nfpad[(((size_t)(pair * 2 + b) * 66 + (y + 1)) * 66 + (x + 1)) * 512 +
                    cg * 8] = *(const int4v*)o;
    __syncthreads();
  }
}

// ---------------- gate conv, coalesced weight reads via [po][tap][ciw][chunk] layout
__global__ __launch_bounds__(256) void k_gate3(const unsigned short* __restrict__ cp,
                                               const unsigned short* __restrict__ nfp,
                                               const float* __restrict__ wgt,
                                               const float* __restrict__ bg,
                                               float* __restrict__ gw) {
  int t = threadIdx.x;
  int z = blockIdx.z;
  int b = z & 1, pair = z >> 1;
  int y = blockIdx.y;
  int x = blockIdx.x * 8 + (t >> 5);
  int chunk = t & 31;
  int ci0 = chunk * 32;
  int half = ci0 >> 9;
  int ch0 = ci0 & 511;
  const unsigned short* src = half ? (nfp + ((size_t)(pair * 2 + b)) * 66 * 66 * 512)
                                   : (cp + ((size_t)b) * 66 * 66 * 512);
  const float* w0b = wgt + ((size_t)(pair * 2 + 0) * 9) * 1024;
  const float* w1b = wgt + ((size_t)(pair * 2 + 1) * 9) * 1024;
  float a0 = 0.f, a1 = 0.f;
  for (int tap = 0; tap < 9; ++tap) {
    int ky = tap / 3, kx = tap % 3;
    const unsigned short* ip = src + ((size_t)(y + ky) * 66 + (x + kx)) * 512 + ch0;
    const float* w0 = w0b + tap * 1024 + chunk;
    const float* w1 = w1b + tap * 1024 + chunk;
#pragma unroll
    for (int q = 0; q < 4; ++q) {
      bf16x8 v8 = *(const bf16x8*)(ip + q * 8);
#pragma unroll
      for (int e = 0; e < 8; e++) {
        float f = b2f((unsigned short)v8[e]);
        a0 += f * w0[(q * 8 + e) * 32];
        a1 += f * w1[(q * 8 + e) * 32];
      }
    }
  }
#pragma unroll
  for (int md = 1; md < 32; md <<= 1) {
    a0 += __shfl_xor(a0, md);
    a1 += __shfl_xor(a1, md);
  }
  if ((t & 31) == 0) {
    float g0 = 1.f / (1.f + __expf(-(a0 + bg[pair * 2 + 0])));
    float g1 = 1.f / (1.f + __expf(-(a1 + bg[pair * 2 + 1])));
    gw[(((size_t)(pair * 2 + b) * 2 + 0) * 64 + y) * 64 + x] = g0;
    gw[(((size_t)(pair * 2 + b) * 2 + 1) * 64 + y) * 64 + x] = g1;
  }
}

// ---------------- fg = [center*g0, nf*g1] -> fgp[pz][2][66][66][1024] bf16
__global__ __launch_bounds__(256) void k_fg(const unsigned short* __restrict__ cp,
                                            const unsigned short* __restrict__ nfp,
                                            const float* __restrict__ gw,
                                            unsigned short* __restrict__ fgp, int pairBase) {
  int pz = blockIdx.y;
  int pair = pairBase + pz;
  unsigned short* dstBase = fgp + (size_t)pz * 2 * 66 * 66 * 1024;
  size_t idx = (size_t)blockIdx.x * 256 + threadIdx.x;
  int chunk = (int)(idx & 127);
  size_t px = idx >> 7;
  int b = (int)(px >> 12), rem = (int)(px & 4095);
  int y = rem >> 6, x = rem & 63;
  int ci0 = chunk * 8;
  int half = ci0 >> 9;
  float g = gw[(((size_t)(pair * 2 + b) * 2 + half) * 64 + y) * 64 + x];
  const unsigned short* src = half ? (nfp + ((size_t)(pair * 2 + b)) * 66 * 66 * 512)
                                   : (cp + (size_t)b * 66 * 66 * 512);
  size_t poff = ((size_t)(y + 1) * 66 + (x + 1)) * 512 + (ci0 - half * 512);
  bf16x8 v = *(const bf16x8*)(src + poff);
  __align__(16) unsigned short o[8];
#pragma unroll
  for (int e = 0; e < 8; e++) o[e] = f2b(b2f((unsigned short)v[e]) * g);
  *(int4v*)(dstBase + ((size_t)(b * 66 + y + 1) * 66 + (x + 1)) * 1024 + ci0) =
      *(const int4v*)o;
}

// ---------------- 256x256x64 phase-templated implicit-GEMM conv (r8-verified
// schedule: stage A@P2, B@P3, vmcnt(8) once per tile; 16x16x32 MFMA, swizzle
// kc^(row&7); conflict-free). stB uses wave-uniform SALU tap decode (verified
// correct in r9's conv6). MODE 0: Wd (+bias+relu). MODE 2: Wc split-K/4.
template <int CI, int MODE>
__global__ __launch_bounds__(512) void conv5(const unsigned short* __restrict__ inB,
                                             const unsigned short* __restrict__ WTb,
                                             const float* __restrict__ bias,
                                             unsigned short* __restrict__ outB,
                                             unsigned short* __restrict__ outP,
                                             int pairOfs, int multiz) {
  constexpr int K = 9 * CI;
  constexpr int KTOT = K / 64;
  constexpr int KT = (MODE == 2) ? KTOT / 4 : KTOT;
  __shared__ unsigned short As[2 * 2 * 8192];
  __shared__ unsigned short Bs[2 * 2 * 8192];

  int t = threadIdx.x;
  int bid = blockIdx.x;
  int xcd = bid & 7;
  int z, m, n;
  if (multiz) {
    z = xcd >> 1; m = xcd & 1; n = bid >> 3;
  } else {
    z = 0; m = bid & 1; n = bid >> 1;
  }
  const unsigned short* inPad = (MODE == 0) ? inB + (size_t)z * 2 * 66 * 66 * 1024 : inB;
  const unsigned short* WT = (MODE == 0) ? WTb + (size_t)z * 512 * 9216 : WTb;
  const int kt0 = (MODE == 2) ? z * KT : 0;
  const int ktEnd = kt0 + KT;
  int co0 = m * 256, n0 = n * 256;

  int rowS[2], kcS[2], linS[2];
  size_t bpix2[2][2];  // [h][rr]: pixel base + (kc&3)*8 pre-added
#pragma unroll
  for (int rr = 0; rr < 2; rr++) {
    int idx2 = rr * 512 + t;
    rowS[rr] = idx2 >> 3;
    kcS[rr] = (idx2 & 7) ^ (rowS[rr] & 7);
    linS[rr] = idx2 * 8;
#pragma unroll
    for (int h = 0; h < 2; h++) {
      int ng = n0 + h * 128 + rowS[rr];
      int bb = ng >> 12, yy = (ng >> 6) & 63, xx = ng & 63;
      bpix2[h][rr] = (size_t)((bb * 66 + yy) * 66 + xx) * CI + (kcS[rr] & 3) * 8;
    }
  }

  f32x4 acc[8][4];
#pragma unroll
  for (int i = 0; i < 8; i++)
#pragma unroll
    for (int j = 0; j < 4; j++) acc[i][j] = f32x4{0.f, 0.f, 0.f, 0.f};

  int wid = t >> 6, l = t & 63;
  int wm = wid >> 2, wn = wid & 3;
  int lrow = l & 15, lk4 = l >> 4;

  auto stA = [&](int bufp, int h, int kt) {
#pragma unroll
    for (int rr = 0; rr < 2; rr++)
      gload16(WT + (size_t)(co0 + h * 128 + rowS[rr]) * K + kt * 64 + kcS[rr] * 8,
              &As[(bufp * 2 + h) * 8192 + linS[rr]]);
  };
  auto stB = [&](int bufp, int h, int kt) {
    // wave-uniform tap decode (kt uniform -> SALU); per-lane just a select
    int g0 = kt * 2, g1 = g0 + 1;
    int cib0 = g0 / 9, tap0 = g0 - cib0 * 9;
    int cib1 = g1 / 9, tap1 = g1 - cib1 * 9;
    int off0 = ((tap0 / 3) * 66 + tap0 % 3) * CI + cib0 * 32;
    int off1 = ((tap1 / 3) * 66 + tap1 % 3) * CI + cib1 * 32;
#pragma unroll
    for (int rr = 0; rr < 2; rr++)
      gload16(inPad + bpix2[h][rr] + ((kcS[rr] & 4) ? off1 : off0),
              &Bs[(bufp * 2 + h) * 8192 + linS[rr]]);
  };

  bf16x8 afr0[4][2], afr1[4][2], bfr0[2][2], bfr1[2][2];

#define RDA(DST, C, MH)                                                         \
  _Pragma("unroll") for (int ii = 0; ii < 4; ++ii) {                            \
    int row = (MH)*64 + ii * 16 + lrow;                                         \
    _Pragma("unroll") for (int kk = 0; kk < 2; ++kk) {                          \
      int pos = (kk * 4 + lk4) ^ (lrow & 7);                                    \
      DST[ii][kk] = *(const bf16x8*)&As[((C)*2 + wm) * 8192 + row * 64 + pos * 8]; \
    }                                                                           \
  }
#define RDB(DST, C, NH)                                                         \
  _Pragma("unroll") for (int j = 0; j < 2; ++j) {                               \
    int row = (wn & 1) * 64 + (NH)*32 + j * 16 + lrow;                          \
    _Pragma("unroll") for (int kk = 0; kk < 2; ++kk) {                          \
      int pos = (kk * 4 + lk4) ^ (lrow & 7);                                    \
      DST[j][kk] =                                                              \
          *(const bf16x8*)&Bs[((C)*2 + (wn >> 1)) * 8192 + row * 64 + pos * 8]; \
    }                                                                           \
  }
#define QUAD(AF, BF, MH, NH)                                                    \
  __builtin_amdgcn_s_setprio(1);                                                \
  _Pragma("unroll") for (int ii = 0; ii < 4; ++ii) {                            \
    _Pragma("unroll") for (int j = 0; j < 2; ++j) {                             \
      _Pragma("unroll") for (int kk = 0; kk < 2; ++kk) {                        \
        acc[(MH)*4 + ii][(NH)*2 + j] = __builtin_amdgcn_mfma_f32_16x16x32_bf16( \
            AF[ii][kk], BF[j][kk], acc[(MH)*4 + ii][(NH)*2 + j], 0, 0, 0);      \
      }                                                                         \
    }                                                                           \
  }                                                                             \
  __builtin_amdgcn_s_setprio(0);
#define LGKM0_FENCE                                        \
  asm volatile("s_waitcnt lgkmcnt(0)" ::: "memory");       \
  __builtin_amdgcn_sched_barrier(0);

  // prologue: stage kt0 -> buf0, kt0+1 -> buf1 (8+8 loads); wait kt0, barrier
  {
    int b0 = kt0 & 1, b1 = b0 ^ 1;
    stA(b0, 0, kt0); stA(b0, 1, kt0); stB(b0, 0, kt0); stB(b0, 1, kt0);
    stA(b1, 0, kt0 + 1); stA(b1, 1, kt0 + 1); stB(b1, 0, kt0 + 1); stB(b1, 1, kt0 + 1);
    asm volatile("s_waitcnt vmcnt(8)" ::: "memory");
    __builtin_amdgcn_s_barrier();
  }

  for (int kt = kt0; kt < ktEnd; ++kt) {
    int cur = kt & 1;
    const bool pf = (kt + 2 < ktEnd);
    // P0: read A-half(MH=0) + B-half(NH=0) frags; no staging
    RDA(afr0, cur, 0);
    RDB(bfr0, cur, 0);
    __builtin_amdgcn_s_barrier();
    LGKM0_FENCE
    QUAD(afr0, bfr0, 0, 0)
    __builtin_amdgcn_s_barrier();
    // P1: read A-half(MH=1); no staging (A slots live until these reads done)
    RDA(afr1, cur, 1);
    __builtin_amdgcn_s_barrier();
    LGKM0_FENCE
    QUAD(afr1, bfr0, 1, 0)
    __builtin_amdgcn_s_barrier();
    // P2: read B-half(NH=1); A fully consumed (P0+P1) -> stage both A halves of kt+2
    RDB(bfr1, cur, 1);
    if (pf) { stA(cur, 0, kt + 2); stA(cur, 1, kt + 2); }
    __builtin_amdgcn_s_barrier();
    LGKM0_FENCE
    QUAD(afr1, bfr1, 1, 1)
    __builtin_amdgcn_s_barrier();
    // P3: B fully consumed (P0+P2) -> stage both B halves of kt+2
    if (pf) { stB(cur, 0, kt + 2); stB(cur, 1, kt + 2); }
    __builtin_amdgcn_sched_barrier(0);
    QUAD(afr0, bfr1, 0, 1)
    if (pf) {
      asm volatile("s_waitcnt vmcnt(8)" ::: "memory");  // kt+1's 8 loads retired
    } else {
      asm volatile("s_waitcnt vmcnt(0)" ::: "memory");
    }
    __builtin_amdgcn_s_barrier();
  }
#undef RDA
#undef RDB
#undef QUAD
#undef LGKM0_FENCE

#pragma unroll
  for (int i = 0; i < 8; i++) {
#pragma unroll
    for (int j = 0; j < 4; j++) {
      int col = wn * 64 + j * 16 + lrow;
      int ng = n0 + col;
      int bb = ng >> 12, yy = (ng >> 6) & 63, xx = ng & 63;
#pragma unroll
      for (int r = 0; r < 4; r++) {
        int row = wm * 128 + i * 16 + lk4 * 4 + r;
        int co = co0 + row;
        if (MODE == 0) {
          int zc = (z + pairOfs) * 512 + co;
          float v = acc[i][j][r] + bias[zc];
          v = v > 0.f ? v : 0.f;
          outB[((size_t)(bb * 66 + yy + 1) * 66 + (xx + 1)) * 2048 + zc] = f2b(v);
        } else {
          outP[((size_t)(z * 512 + co) << 13) + ng] = f2b(acc[i][j][r]);
        }
      }
    }
  }
}

// ---------------- combine split-K bf16 partials: out = relu(sum + bias), f32 NCHW
__global__ __launch_bounds__(256) void k_combine2(const unsigned short* __restrict__ p,
                                                  const float* __restrict__ bc,
                                                  float* __restrict__ out) {
  size_t i8 = ((size_t)blockIdx.x * 256 + threadIdx.x) * 8;  // over 512*8192
  int co = (int)(i8 >> 13);
  int ng = (int)(i8 & 8191);
  float s[8] = {0.f, 0.f, 0.f, 0.f, 0.f, 0.f, 0.f, 0.f};
#pragma unroll
  for (int zz = 0; zz < 4; zz++) {
    bf16x8 v = *(const bf16x8*)&p[((size_t)(zz * 512 + co) << 13) + ng];
#pragma unroll
    for (int e = 0; e < 8; e++) s[e] += b2f((unsigned short)v[e]);
  }
  float bb = bc[co];
  int batch = ng >> 12, rem = ng & 4095;
  float* o = out + (((size_t)(batch * 512 + co)) << 12) + rem;
#pragma unroll
  for (int e = 0; e < 8; e++) {
    float q = s[e] + bb;
    o[e] = q > 0.f ? q : 0.f;
  }
}

extern "C" void kernel_launch(void* const* d_in, const int* in_sizes, int n_in,
                              void* d_out, int out_size, void* d_ws, size_t ws_size,
                              hipStream_t stream) {
  const float* x = (const float*)d_in[0];
  const float* Wg = (const float*)d_in[1];
  const float* bg = (const float*)d_in[2];
  const float* Wd = (const float*)d_in[3];
  const float* bd = (const float*)d_in[4];
  const float* Wc = (const float*)d_in[5];
  const float* bc = (const float*)d_in[6];
  float* out = (float*)d_out;

  char* ws = (char*)d_ws;
  size_t off = 0;
  auto alloc = [&](size_t bytes) {
    void* p = ws + off;
    off = (off + bytes + 255) & ~(size_t)255;
    return p;
  };
  const size_t SZ_WDT = (size_t)2048 * 9216 * 2;
  const size_t SZ_WCT = (size_t)512 * 18432 * 2;
  const size_t SZ_WGT = (size_t)4 * 2 * 9 * 1024 * 4;
  const size_t SZ_CP = (size_t)2 * 66 * 66 * 512 * 2;
  const size_t SZ_NF = (size_t)4 * 2 * 66 * 66 * 512 * 2;
  const size_t SZ_GT = (size_t)2 * 66 * 66 * 2048 * 2;
  const size_t SZ_GW = (size_t)4 * 2 * 2 * 4096 * 4;
  const size_t SZ_XF1 = (size_t)4 * 2 * 68 * 68 * 512 * 2;
  const size_t SZ_CORR = (size_t)4 * 2 * 25 * 4096 * 4;
  const size_t SZ_FG1 = (size_t)2 * 66 * 66 * 1024 * 2;
  const size_t SZ_FG4 = SZ_FG1 * 4;

  unsigned short* WdT = (unsigned short*)alloc(SZ_WDT);
  unsigned short* WcT = (unsigned short*)alloc(SZ_WCT);
  float* WgT = (float*)alloc(SZ_WGT);
  unsigned short* centerpad = (unsigned short*)alloc(SZ_CP);
  unsigned short* nfpad = (unsigned short*)alloc(SZ_NF);
  unsigned short* gatedpad = (unsigned short*)alloc(SZ_GT);
  float* gw = (float*)alloc(SZ_GW);
  unsigned* maxb = (unsigned*)alloc(256);

  // union region: phase1 {xf1, corr, cpart} -> phase2 {fg} -> phase3 {wcp}
  size_t unionOff = off;
  unsigned short* xf1 = (unsigned short*)(ws + unionOff);
  size_t o2 = unionOff + ((SZ_XF1 + 255) & ~(size_t)255);
  float* corr = (float*)(ws + o2);
  float* cpart = (float*)(ws + o2 + ((SZ_CORR + 255) & ~(size_t)255));
  unsigned short* fg = (unsigned short*)(ws + unionOff);
  unsigned short* wcp = (unsigned short*)(ws + unionOff);
  bool batched = ws_size >= unionOff + SZ_FG4;

  hipMemsetAsync(maxb, 0, 64, stream);

  // zero pad rings of buffers NOT aliased with the live union region
  k_border<<<512, 256, 0, stream>>>(xf1, 68, 2, 64, 8);
  k_border<<<512, 256, 0, stream>>>(centerpad, 66, 1, 64, 2);
  k_border<<<512, 256, 0, stream>>>(nfpad, 66, 1, 64, 8);
  k_border<<<512, 256, 0, stream>>>(gatedpad, 66, 1, 256, 2);

  k_reorder_w2<<<2048, 256, 0, stream>>>(Wd, WdT, 1024);
  k_reorder_w2<<<512, 256, 0, stream>>>(Wc, WcT, 2048);
  k_reorder_wg<<<288, 256, 0, stream>>>(Wg, WgT);
  k_pad<<<dim3(64, 10), 256, 0, stream>>>(x, xf1, centerpad);
  k_corr<<<dim3(4, 4, 32), 256, 0, stream>>>(x, cpart);
  k_corr_combine<<<dim3(200, 4), 256, 0, stream>>>(cpart, corr, maxb);
  k_attn3<<<dim3(4, 4, 128), 256, 0, stream>>>(xf1, corr, maxb, nfpad);
  k_gate3<<<dim3(8, 64, 8), 256, 0, stream>>>(centerpad, nfpad, WgT, bg, gw);

  // xf1/corr/cpart are dead NOW -> safe to zero fg's pad ring (fg aliases them)
  k_border<<<512, 256, 0, stream>>>(fg, 66, 1, 128, batched ? 8 : 2);

  if (batched) {
    k_fg<<<dim3(4096, 4), 256, 0, stream>>>(centerpad, nfpad, gw, fg, 0);
    conv5<1024, 0><<<256, 512, 0, stream>>>(fg, WdT, bd, gatedpad, nullptr, 0, 1);
  } else {
    for (int pair = 0; pair < 4; ++pair) {
      k_fg<<<dim3(4096, 1), 256, 0, stream>>>(centerpad, nfpad, gw, fg, pair);
      conv5<1024, 0><<<64, 512, 0, stream>>>(
          fg, WdT + (size_t)pair * 512 * 9216, bd, gatedpad, nullptr, pair, 0);
    }
  }
  conv5<2048, 2><<<256, 512, 0, stream>>>(gatedpad, WcT, nullptr, nullptr, wcp, 0, 1);
  k_combine2<<<2048, 256, 0, stream>>>(wcp, bc, out);
}

// Round 11
// 786.541 us; speedup vs baseline: 1.1120x; 1.0471x over previous
//
#include <hip/hip_runtime.h>
#include <hip/hip_bf16.h>
#include <stdint.h>

typedef __attribute__((ext_vector_type(8))) short bf16x8;
typedef __attribute__((ext_vector_type(4))) float f32x4;
typedef __attribute__((ext_vector_type(4))) int int4v;

#define DEVI static __device__ __forceinline__

DEVI unsigned short f2b(float f) {
  union { float f; unsigned u; } v; v.f = f;
  unsigned r = (v.u + 0x7FFFu + ((v.u >> 16) & 1u)) >> 16;
  return (unsigned short)r;
}
DEVI float b2f(unsigned short h) {
  union { unsigned u; float f; } v; v.u = ((unsigned)h) << 16;
  return v.f;
}
DEVI unsigned encf(float f) {
  union { float f; unsigned u; } v; v.f = f;
  return (v.u & 0x80000000u) ? ~v.u : (v.u | 0x80000000u);
}
DEVI float decf(unsigned u) {
  union { unsigned u; float f; } v;
  v.u = (u & 0x80000000u) ? (u & 0x7FFFFFFFu) : ~u;
  return v.f;
}
DEVI void gload16(const void* g, void* l) {
  __builtin_amdgcn_global_load_lds(
      (const __attribute__((address_space(1))) unsigned int*)g,
      (__attribute__((address_space(3))) unsigned int*)l, 16, 0, 0);
}

// ---------------- weight reorder: dst[r][cib][tap][ci32] bf16 <- src[r][ci][tap] f32
__global__ __launch_bounds__(256) void k_reorder_w2(const float* __restrict__ src,
                                                    unsigned short* __restrict__ dst,
                                                    int CI) {
  int r = blockIdx.x;
  int t = threadIdx.x;
  const float* s = src + (size_t)r * CI * 9;
  unsigned short* d = dst + (size_t)r * CI * 9;
  for (int ci0 = 0; ci0 < CI; ci0 += 256) {
    int ci = ci0 + t;
    float v[9];
#pragma unroll
    for (int k = 0; k < 9; k++) v[k] = s[(size_t)ci * 9 + k];
    unsigned short* db = d + (size_t)(ci >> 5) * 288 + (ci & 31);
#pragma unroll
    for (int k = 0; k < 9; k++) db[(size_t)k * 32] = f2b(v[k]);
  }
}

// WgT[po][tap][ciw32][chunk32] f32 <- Wg[po][ci][tap]  (ci = chunk*32 + ciw)
__global__ void k_reorder_wg(const float* __restrict__ src, float* __restrict__ dst) {
  int idx = blockIdx.x * 256 + threadIdx.x;  // total 73728
  int ci = idx & 1023;
  int rt = idx >> 10;
  int tap = rt % 9;
  int po = rt / 9;
  dst[(((size_t)po * 9 + tap) * 32 + (ci & 31)) * 32 + (ci >> 5)] =
      src[((size_t)po * 1024 + ci) * 9 + tap];
}

// ---------------- zero the pad ring of an NHWC buffer (replaces big memsets)
__global__ void k_border(unsigned short* __restrict__ p, int H, int wpad, int C8,
                         int nImg) {
  int inner = H - 2 * wpad;
  int borderPx = H * H - inner * inner;
  long total = (long)borderPx * C8 * nImg;
  int topN = wpad * H;
  for (long i = (long)blockIdx.x * 256 + threadIdx.x; i < total;
       i += (long)gridDim.x * 256) {
    int c = (int)(i % C8);
    long r2 = i / C8;
    int px = (int)(r2 % borderPx);
    int img = (int)(r2 / borderPx);
    int y, x;
    if (px < topN) {
      y = px / H; x = px % H;
    } else if (px < 2 * topN) {
      int q = px - topN; y = H - 1 - (q / H); x = q % H;
    } else {
      int q = px - 2 * topN;
      int row = q / (2 * wpad), cc = q % (2 * wpad);
      y = wpad + row;
      x = cc < wpad ? cc : H - 2 * wpad + cc;
    }
    *(int4v*)&p[((((size_t)img * H + y) * H + x) * C8 + c) * 8] = int4v{0, 0, 0, 0};
  }
}

// ---------------- pad/transpose: x NCHW f32 -> NHWC bf16
__global__ __launch_bounds__(256) void k_pad(const float* __restrict__ xin,
                                             unsigned short* __restrict__ xf1,
                                             unsigned short* __restrict__ cp) {
  __shared__ unsigned short lds[64 * 66];
  int t = threadIdx.x;
  int y = blockIdx.x;   // 0..63
  int fb = blockIdx.y;  // 0..9 = f*2+b
  int f = fb >> 1, b = fb & 1;
  const float* src = xin + (size_t)fb * 512 * 4096 + y * 64;
  unsigned short* base;
  if (f == 2) {
    base = cp + (((size_t)b * 66) + y + 1) * 66 * 512 + 512;
  } else {
    int fi = f < 2 ? f : f - 1;
    base = xf1 + (((size_t)(fi * 2 + b) * 68) + y + 2) * 68 * 512 + 2 * 512;
  }
  for (int c0 = 0; c0 < 512; c0 += 64) {
#pragma unroll
    for (int r = 0; r < 16; ++r) {
      int ci = r * 4 + (t >> 6);
      int xx = t & 63;
      lds[ci * 66 + xx] = f2b(src[(size_t)(c0 + ci) * 4096 + xx]);
    }
    __syncthreads();
    int xp = t >> 2;
    int cc = (t & 3) * 16;
    __align__(16) unsigned short vals[16];
#pragma unroll
    for (int i = 0; i < 16; i++) vals[i] = lds[(cc + i) * 66 + xp];
    unsigned short* dst = base + (size_t)xp * 512 + c0 + cc;
    *(int4v*)(dst) = *(const int4v*)(vals);
    *(int4v*)(dst + 8) = *(const int4v*)(vals + 8);
    __syncthreads();
  }
}

// ---------------- correlation partials (f32): corrpart[part][pair][b][25][64][64]
__global__ __launch_bounds__(256) void k_corr(const float* __restrict__ xin,
                                              float* __restrict__ corrpart) {
  __shared__ float f1h[840];  // [2][20][21]
  int t = threadIdx.x;
  int tx = t & 15, ty = t >> 4;
  int x0 = blockIdx.x * 16, y0 = blockIdx.y * 16;
  int z = blockIdx.z;
  int b = z & 1, pair = (z >> 1) & 3, part = z >> 3;
  int s = pair < 2 ? pair : pair + 1;
  const float* f2 = xin + ((size_t)(2 * 2 + b) * 512) * 4096;
  const float* f1 = xin + ((size_t)(s * 2 + b) * 512) * 4096;

  int cnt = (t < 32) ? 4 : 3;
  int ldso[4], goff[4], chv[4];
  bool val[4];
#pragma unroll
  for (int q = 0; q < 4; q++) {
    int k = t + q * 256;
    if (k >= 800) k = 799;
    int ch = k >= 400;
    int e = k - ch * 400;
    int r = e / 20, cc = e - r * 20;
    int gy = y0 + r - 2, gx = x0 + cc - 2;
    val[q] = ((unsigned)gy < 64u) && ((unsigned)gx < 64u);
    ldso[q] = ch * 420 + r * 21 + cc;
    goff[q] = gy * 64 + gx;
    chv[q] = ch;
  }

  float acc[25];
#pragma unroll
  for (int d = 0; d < 25; d++) acc[d] = 0.f;
  int y = y0 + ty, x = x0 + tx;
  for (int c = part * 128; c < part * 128 + 128; c += 2) {
#pragma unroll
    for (int q = 0; q < 4; q++) {
      if (q < cnt) {
        float v = 0.f;
        if (val[q]) v = f1[(size_t)(c + chv[q]) * 4096 + goff[q]];
        f1h[ldso[q]] = v;
      }
    }
    float f2a = f2[(size_t)c * 4096 + y * 64 + x];
    float f2c = f2[(size_t)(c + 1) * 4096 + y * 64 + x];
    __syncthreads();
#pragma unroll
    for (int d = 0; d < 25; ++d) {
      int di = d / 5, dj = d % 5;
      acc[d] += f2a * f1h[(ty + di) * 21 + tx + dj] +
                f2c * f1h[420 + (ty + di) * 21 + tx + dj];
    }
    __syncthreads();
  }
  float* out = corrpart + ((size_t)((part * 4 + pair) * 2 + b) * 25) * 4096;
#pragma unroll
  for (int d = 0; d < 25; d++) out[(size_t)d * 4096 + y * 64 + x] = acc[d];
}

// ---------------- combine partials + global max per pair
__global__ __launch_bounds__(256) void k_corr_combine(const float* __restrict__ cpart,
                                                      float* __restrict__ corr,
                                                      unsigned* __restrict__ maxb) {
  const size_t PERPAIR = (size_t)2 * 25 * 4096;
  int pair = blockIdx.y;
  size_t i4 = ((size_t)blockIdx.x * 256 + threadIdx.x) * 4;
  f32x4 sacc = {0.f, 0.f, 0.f, 0.f};
#pragma unroll
  for (int p = 0; p < 4; p++)
    sacc += *(const f32x4*)(cpart + ((size_t)(p * 4 + pair)) * PERPAIR + i4);
  *(f32x4*)(corr + (size_t)pair * PERPAIR + i4) = sacc;
  float m = fmaxf(fmaxf(sacc[0], sacc[1]), fmaxf(sacc[2], sacc[3]));
#pragma unroll
  for (int off = 32; off; off >>= 1) m = fmaxf(m, __shfl_xor(m, off));
  __shared__ float wm[4];
  if ((threadIdx.x & 63) == 0) wm[threadIdx.x >> 6] = m;
  __syncthreads();
  if (threadIdx.x == 0) {
    float mm = fmaxf(fmaxf(wm[0], wm[1]), fmaxf(wm[2], wm[3]));
    atomicMax(maxb + pair, encf(mm));
  }
}

// ---------------- softmax + 5x5 gather from bf16 NHWC -> nfpad [pair][b][66][66][512]
__global__ __launch_bounds__(256) void k_attn3(const unsigned short* __restrict__ xf1,
                                               const float* __restrict__ corr,
                                               const unsigned* __restrict__ maxb,
                                               unsigned short* __restrict__ nfpad) {
  __shared__ unsigned short f1t[400 * 8];
  int t = threadIdx.x;
  int tx = t & 15, ty = t >> 4;
  int x0 = blockIdx.x * 16, y0 = blockIdx.y * 16;
  int z = blockIdx.z;
  int b = z & 1, pair = (z >> 1) & 3, cgh = z >> 3;
  const unsigned short* f1 = xf1 + ((size_t)(pair * 2 + b)) * 68 * 68 * 512;
  int y = y0 + ty, x = x0 + tx;
  const float* cr = corr + ((size_t)(pair * 2 + b)) * 25 * 4096 + y * 64 + x;

  int r0 = t / 20, c0 = t - r0 * 20;
  size_t go0 = ((size_t)(y0 + r0) * 68 + (x0 + c0)) * 512;
  bool has1 = t < 144;
  int k1 = t + 256;
  int r1 = k1 / 20, c1 = k1 - r1 * 20;
  size_t go1 = ((size_t)(y0 + r1) * 68 + (x0 + c1)) * 512;

  float p[25];
  float mx = -1e30f;
#pragma unroll
  for (int d = 0; d < 25; d++) {
    p[d] = cr[(size_t)d * 4096];
    mx = fmaxf(mx, p[d]);
  }
  float gs = 20.f / decf(maxb[pair]);
  float ss = 0.f;
#pragma unroll
  for (int d = 0; d < 25; d++) {
    p[d] = __expf((p[d] - mx) * gs);
    ss += p[d];
  }
  float inv = 1.f / ss;
#pragma unroll
  for (int d = 0; d < 25; d++) p[d] *= inv;

  for (int q = 0; q < 4; ++q) {
    int cg = cgh * 4 + q;
    *(int4v*)&f1t[t * 8] = *(const int4v*)&f1[go0 + cg * 8];
    if (has1) *(int4v*)&f1t[k1 * 8] = *(const int4v*)&f1[go1 + cg * 8];
    __syncthreads();
    float acc[8] = {0.f, 0.f, 0.f, 0.f, 0.f, 0.f, 0.f, 0.f};
#pragma unroll
    for (int d = 0; d < 25; d++) {
      bf16x8 v = *(const bf16x8*)&f1t[((ty + d / 5) * 20 + tx + d % 5) * 8];
      float pd = p[d];
#pragma unroll
      for (int e = 0; e < 8; e++) acc[e] += pd * b2f((unsigned short)v[e]);
    }
    __align__(16) unsigned short o[8];
#pragma unroll
    for (int e = 0; e < 8; e++) o[e] = f2b(acc[e]);
    *(int4v*)&nfpad[(((size_t)(pair * 2 + b) * 66 + (y + 1)) * 66 + (x + 1)) * 512 +
                    cg * 8] = *(const int4v*)o;
    __syncthreads();
  }
}

// ---------------- gate conv, coalesced weight reads via [po][tap][ciw][chunk] layout
__global__ __launch_bounds__(256) void k_gate3(const unsigned short* __restrict__ cp,
                                               const unsigned short* __restrict__ nfp,
                                               const float* __restrict__ wgt,
                                               const float* __restrict__ bg,
                                               float* __restrict__ gw) {
  int t = threadIdx.x;
  int z = blockIdx.z;
  int b = z & 1, pair = z >> 1;
  int y = blockIdx.y;
  int x = blockIdx.x * 8 + (t >> 5);
  int chunk = t & 31;
  int ci0 = chunk * 32;
  int half = ci0 >> 9;
  int ch0 = ci0 & 511;
  const unsigned short* src = half ? (nfp + ((size_t)(pair * 2 + b)) * 66 * 66 * 512)
                                   : (cp + ((size_t)b) * 66 * 66 * 512);
  const float* w0b = wgt + ((size_t)(pair * 2 + 0) * 9) * 1024;
  const float* w1b = wgt + ((size_t)(pair * 2 + 1) * 9) * 1024;
  float a0 = 0.f, a1 = 0.f;
  for (int tap = 0; tap < 9; ++tap) {
    int ky = tap / 3, kx = tap % 3;
    const unsigned short* ip = src + ((size_t)(y + ky) * 66 + (x + kx)) * 512 + ch0;
    const float* w0 = w0b + tap * 1024 + chunk;
    const float* w1 = w1b + tap * 1024 + chunk;
#pragma unroll
    for (int q = 0; q < 4; ++q) {
      bf16x8 v8 = *(const bf16x8*)(ip + q * 8);
#pragma unroll
      for (int e = 0; e < 8; e++) {
        float f = b2f((unsigned short)v8[e]);
        a0 += f * w0[(q * 8 + e) * 32];
        a1 += f * w1[(q * 8 + e) * 32];
      }
    }
  }
#pragma unroll
  for (int md = 1; md < 32; md <<= 1) {
    a0 += __shfl_xor(a0, md);
    a1 += __shfl_xor(a1, md);
  }
  if ((t & 31) == 0) {
    float g0 = 1.f / (1.f + __expf(-(a0 + bg[pair * 2 + 0])));
    float g1 = 1.f / (1.f + __expf(-(a1 + bg[pair * 2 + 1])));
    gw[(((size_t)(pair * 2 + b) * 2 + 0) * 64 + y) * 64 + x] = g0;
    gw[(((size_t)(pair * 2 + b) * 2 + 1) * 64 + y) * 64 + x] = g1;
  }
}

// ---------------- fg = [center*g0, nf*g1] -> fgp[pz][2][66][66][1024] bf16
__global__ __launch_bounds__(256) void k_fg(const unsigned short* __restrict__ cp,
                                            const unsigned short* __restrict__ nfp,
                                            const float* __restrict__ gw,
                                            unsigned short* __restrict__ fgp, int pairBase) {
  int pz = blockIdx.y;
  int pair = pairBase + pz;
  unsigned short* dstBase = fgp + (size_t)pz * 2 * 66 * 66 * 1024;
  size_t idx = (size_t)blockIdx.x * 256 + threadIdx.x;
  int chunk = (int)(idx & 127);
  size_t px = idx >> 7;
  int b = (int)(px >> 12), rem = (int)(px & 4095);
  int y = rem >> 6, x = rem & 63;
  int ci0 = chunk * 8;
  int half = ci0 >> 9;
  float g = gw[(((size_t)(pair * 2 + b) * 2 + half) * 64 + y) * 64 + x];
  const unsigned short* src = half ? (nfp + ((size_t)(pair * 2 + b)) * 66 * 66 * 512)
                                   : (cp + (size_t)b * 66 * 66 * 512);
  size_t poff = ((size_t)(y + 1) * 66 + (x + 1)) * 512 + (ci0 - half * 512);
  bf16x8 v = *(const bf16x8*)(src + poff);
  __align__(16) unsigned short o[8];
#pragma unroll
  for (int e = 0; e < 8; e++) o[e] = f2b(b2f((unsigned short)v[e]) * g);
  *(int4v*)(dstBase + ((size_t)(b * 66 + y + 1) * 66 + (x + 1)) * 1024 + ci0) =
      *(const int4v*)o;
}

// ---------------- 256x256x64 implicit-GEMM conv, 3-region schedule:
// drains AFTER consumption (lgkm(0) just before each region-end barrier, where
// lgkm is already ~0 because every frag was consumed by that region's MFMAs via
// compiler-counted waits) -> ds_read/MFMA overlap inside regions. Same hazard
// invariant as the verified r8 kernel: every wave provably drained before the
// barrier that precedes any restage of that LDS buffer. vmcnt(8) once per tile.
// 16x16x32 MFMA, swizzle kc^(row&7) (0 conflicts), SALU tap decode.
// MODE 0: Wd (+bias+relu). MODE 2: Wc split-K/4, bf16 partials.
template <int CI, int MODE>
__global__ __launch_bounds__(512) void conv5(const unsigned short* __restrict__ inB,
                                             const unsigned short* __restrict__ WTb,
                                             const float* __restrict__ bias,
                                             unsigned short* __restrict__ outB,
                                             unsigned short* __restrict__ outP,
                                             int pairOfs, int multiz) {
  constexpr int K = 9 * CI;
  constexpr int KTOT = K / 64;
  constexpr int KT = (MODE == 2) ? KTOT / 4 : KTOT;
  __shared__ unsigned short As[2 * 2 * 8192];
  __shared__ unsigned short Bs[2 * 2 * 8192];

  int t = threadIdx.x;
  int bid = blockIdx.x;
  int xcd = bid & 7;
  int z, m, n;
  if (multiz) {
    z = xcd >> 1; m = xcd & 1; n = bid >> 3;
  } else {
    z = 0; m = bid & 1; n = bid >> 1;
  }
  const unsigned short* inPad = (MODE == 0) ? inB + (size_t)z * 2 * 66 * 66 * 1024 : inB;
  const unsigned short* WT = (MODE == 0) ? WTb + (size_t)z * 512 * 9216 : WTb;
  const int kt0 = (MODE == 2) ? z * KT : 0;
  const int ktEnd = kt0 + KT;
  int co0 = m * 256, n0 = n * 256;

  int rowS[2], kcS[2], linS[2];
  size_t bpix2[2][2];
#pragma unroll
  for (int rr = 0; rr < 2; rr++) {
    int idx2 = rr * 512 + t;
    rowS[rr] = idx2 >> 3;
    kcS[rr] = (idx2 & 7) ^ (rowS[rr] & 7);
    linS[rr] = idx2 * 8;
#pragma unroll
    for (int h = 0; h < 2; h++) {
      int ng = n0 + h * 128 + rowS[rr];
      int bb = ng >> 12, yy = (ng >> 6) & 63, xx = ng & 63;
      bpix2[h][rr] = (size_t)((bb * 66 + yy) * 66 + xx) * CI + (kcS[rr] & 3) * 8;
    }
  }

  f32x4 acc[8][4];
#pragma unroll
  for (int i = 0; i < 8; i++)
#pragma unroll
    for (int j = 0; j < 4; j++) acc[i][j] = f32x4{0.f, 0.f, 0.f, 0.f};

  int wid = t >> 6, l = t & 63;
  int wm = wid >> 2, wn = wid & 3;
  int lrow = l & 15, lk4 = l >> 4;

  auto stA = [&](int bufp, int h, int kt) {
#pragma unroll
    for (int rr = 0; rr < 2; rr++)
      gload16(WT + (size_t)(co0 + h * 128 + rowS[rr]) * K + kt * 64 + kcS[rr] * 8,
              &As[(bufp * 2 + h) * 8192 + linS[rr]]);
  };
  auto stB = [&](int bufp, int h, int kt) {
    int g0 = kt * 2, g1 = g0 + 1;
    int cib0 = g0 / 9, tap0 = g0 - cib0 * 9;
    int cib1 = g1 / 9, tap1 = g1 - cib1 * 9;
    int off0 = ((tap0 / 3) * 66 + tap0 % 3) * CI + cib0 * 32;
    int off1 = ((tap1 / 3) * 66 + tap1 % 3) * CI + cib1 * 32;
#pragma unroll
    for (int rr = 0; rr < 2; rr++)
      gload16(inPad + bpix2[h][rr] + ((kcS[rr] & 4) ? off1 : off0),
              &Bs[(bufp * 2 + h) * 8192 + linS[rr]]);
  };

  bf16x8 afr0[4][2], afr1[4][2], bfr0[2][2], bfr1[2][2];

#define RDA(DST, C, MH)                                                         \
  _Pragma("unroll") for (int ii = 0; ii < 4; ++ii) {                            \
    int row = (MH)*64 + ii * 16 + lrow;                                         \
    _Pragma("unroll") for (int kk = 0; kk < 2; ++kk) {                          \
      int pos = (kk * 4 + lk4) ^ (lrow & 7);                                    \
      DST[ii][kk] = *(const bf16x8*)&As[((C)*2 + wm) * 8192 + row * 64 + pos * 8]; \
    }                                                                           \
  }
#define RDB(DST, C, NH)                                                         \
  _Pragma("unroll") for (int j = 0; j < 2; ++j) {                               \
    int row = (wn & 1) * 64 + (NH)*32 + j * 16 + lrow;                          \
    _Pragma("unroll") for (int kk = 0; kk < 2; ++kk) {                          \
      int pos = (kk * 4 + lk4) ^ (lrow & 7);                                    \
      DST[j][kk] =                                                              \
          *(const bf16x8*)&Bs[((C)*2 + (wn >> 1)) * 8192 + row * 64 + pos * 8]; \
    }                                                                           \
  }
#define QUAD(AF, BF, MH, NH)                                                    \
  __builtin_amdgcn_s_setprio(1);                                                \
  _Pragma("unroll") for (int ii = 0; ii < 4; ++ii) {                            \
    _Pragma("unroll") for (int j = 0; j < 2; ++j) {                             \
      _Pragma("unroll") for (int kk = 0; kk < 2; ++kk) {                        \
        acc[(MH)*4 + ii][(NH)*2 + j] = __builtin_amdgcn_mfma_f32_16x16x32_bf16( \
            AF[ii][kk], BF[j][kk], acc[(MH)*4 + ii][(NH)*2 + j], 0, 0, 0);      \
      }                                                                         \
    }                                                                           \
  }                                                                             \
  __builtin_amdgcn_s_setprio(0);
#define DRAIN_LGKM asm volatile("s_waitcnt lgkmcnt(0)" ::: "memory");

  // prologue: stage kt0 -> buf0, kt0+1 -> buf1 (8+8 loads); wait kt0, barrier
  {
    int b0 = kt0 & 1, b1 = b0 ^ 1;
    stA(b0, 0, kt0); stA(b0, 1, kt0); stB(b0, 0, kt0); stB(b0, 1, kt0);
    stA(b1, 0, kt0 + 1); stA(b1, 1, kt0 + 1); stB(b1, 0, kt0 + 1); stB(b1, 1, kt0 + 1);
    asm volatile("s_waitcnt vmcnt(8)" ::: "memory");
    __builtin_amdgcn_s_barrier();
  }

  for (int kt = kt0; kt < ktEnd; ++kt) {
    int cur = kt & 1;
    const bool pf = (kt + 2 < ktEnd);
    // R1: all A reads + B-half0 reads + 2 quads; compiler emits counted lgkm
    // waits -> ds_read/MFMA overlap. Full drain only at region end (cheap:
    // everything already consumed), guaranteeing cross-wave restage safety.
    RDA(afr0, cur, 0);
    RDB(bfr0, cur, 0);
    QUAD(afr0, bfr0, 0, 0)
    RDA(afr1, cur, 1);
    QUAD(afr1, bfr0, 1, 0)
    DRAIN_LGKM
    __builtin_amdgcn_s_barrier();
    // R2: restage A(kt+2) into cur (all waves' A reads provably drained);
    // read B-half1; quad 11.
    if (pf) { stA(cur, 0, kt + 2); stA(cur, 1, kt + 2); }
    RDB(bfr1, cur, 1);
    QUAD(afr1, bfr1, 1, 1)
    DRAIN_LGKM
    __builtin_amdgcn_s_barrier();
    // R3: restage B(kt+2) (all waves' B reads drained); quad 01; counted vmcnt.
    if (pf) { stB(cur, 0, kt + 2); stB(cur, 1, kt + 2); }
    QUAD(afr0, bfr1, 0, 1)
    if (pf) {
      asm volatile("s_waitcnt vmcnt(8)" ::: "memory");  // kt+1's 8 loads retired
    } else {
      asm volatile("s_waitcnt vmcnt(0)" ::: "memory");
    }
    __builtin_amdgcn_s_barrier();
  }
#undef RDA
#undef RDB
#undef QUAD
#undef DRAIN_LGKM

#pragma unroll
  for (int i = 0; i < 8; i++) {
#pragma unroll
    for (int j = 0; j < 4; j++) {
      int col = wn * 64 + j * 16 + lrow;
      int ng = n0 + col;
      int bb = ng >> 12, yy = (ng >> 6) & 63, xx = ng & 63;
#pragma unroll
      for (int r = 0; r < 4; r++) {
        int row = wm * 128 + i * 16 + lk4 * 4 + r;
        int co = co0 + row;
        if (MODE == 0) {
          int zc = (z + pairOfs) * 512 + co;
          float v = acc[i][j][r] + bias[zc];
          v = v > 0.f ? v : 0.f;
          outB[((size_t)(bb * 66 + yy + 1) * 66 + (xx + 1)) * 2048 + zc] = f2b(v);
        } else {
          outP[((size_t)(z * 512 + co) << 13) + ng] = f2b(acc[i][j][r]);
        }
      }
    }
  }
}

// ---------------- combine split-K bf16 partials: out = relu(sum + bias), f32 NCHW
__global__ __launch_bounds__(256) void k_combine2(const unsigned short* __restrict__ p,
                                                  const float* __restrict__ bc,
                                                  float* __restrict__ out) {
  size_t i8 = ((size_t)blockIdx.x * 256 + threadIdx.x) * 8;  // over 512*8192
  int co = (int)(i8 >> 13);
  int ng = (int)(i8 & 8191);
  float s[8] = {0.f, 0.f, 0.f, 0.f, 0.f, 0.f, 0.f, 0.f};
#pragma unroll
  for (int zz = 0; zz < 4; zz++) {
    bf16x8 v = *(const bf16x8*)&p[((size_t)(zz * 512 + co) << 13) + ng];
#pragma unroll
    for (int e = 0; e < 8; e++) s[e] += b2f((unsigned short)v[e]);
  }
  float bb = bc[co];
  int batch = ng >> 12, rem = ng & 4095;
  float* o = out + (((size_t)(batch * 512 + co)) << 12) + rem;
#pragma unroll
  for (int e = 0; e < 8; e++) {
    float q = s[e] + bb;
    o[e] = q > 0.f ? q : 0.f;
  }
}

extern "C" void kernel_launch(void* const* d_in, const int* in_sizes, int n_in,
                              void* d_out, int out_size, void* d_ws, size_t ws_size,
                              hipStream_t stream) {
  const float* x = (const float*)d_in[0];
  const float* Wg = (const float*)d_in[1];
  const float* bg = (const float*)d_in[2];
  const float* Wd = (const float*)d_in[3];
  const float* bd = (const float*)d_in[4];
  const float* Wc = (const float*)d_in[5];
  const float* bc = (const float*)d_in[6];
  float* out = (float*)d_out;

  char* ws = (char*)d_ws;
  size_t off = 0;
  auto alloc = [&](size_t bytes) {
    void* p = ws + off;
    off = (off + bytes + 255) & ~(size_t)255;
    return p;
  };
  const size_t SZ_WDT = (size_t)2048 * 9216 * 2;
  const size_t SZ_WCT = (size_t)512 * 18432 * 2;
  const size_t SZ_WGT = (size_t)4 * 2 * 9 * 1024 * 4;
  const size_t SZ_CP = (size_t)2 * 66 * 66 * 512 * 2;
  const size_t SZ_NF = (size_t)4 * 2 * 66 * 66 * 512 * 2;
  const size_t SZ_GT = (size_t)2 * 66 * 66 * 2048 * 2;
  const size_t SZ_GW = (size_t)4 * 2 * 2 * 4096 * 4;
  const size_t SZ_XF1 = (size_t)4 * 2 * 68 * 68 * 512 * 2;
  const size_t SZ_CORR = (size_t)4 * 2 * 25 * 4096 * 4;
  const size_t SZ_FG1 = (size_t)2 * 66 * 66 * 1024 * 2;
  const size_t SZ_FG4 = SZ_FG1 * 4;

  unsigned short* WdT = (unsigned short*)alloc(SZ_WDT);
  unsigned short* WcT = (unsigned short*)alloc(SZ_WCT);
  float* WgT = (float*)alloc(SZ_WGT);
  unsigned short* centerpad = (unsigned short*)alloc(SZ_CP);
  unsigned short* nfpad = (unsigned short*)alloc(SZ_NF);
  unsigned short* gatedpad = (unsigned short*)alloc(SZ_GT);
  float* gw = (float*)alloc(SZ_GW);
  unsigned* maxb = (unsigned*)alloc(256);

  // union region: phase1 {xf1, corr, cpart} -> phase2 {fg} -> phase3 {wcp}
  size_t unionOff = off;
  unsigned short* xf1 = (unsigned short*)(ws + unionOff);
  size_t o2 = unionOff + ((SZ_XF1 + 255) & ~(size_t)255);
  float* corr = (float*)(ws + o2);
  float* cpart = (float*)(ws + o2 + ((SZ_CORR + 255) & ~(size_t)255));
  unsigned short* fg = (unsigned short*)(ws + unionOff);
  unsigned short* wcp = (unsigned short*)(ws + unionOff);
  bool batched = ws_size >= unionOff + SZ_FG4;

  hipMemsetAsync(maxb, 0, 64, stream);

  // zero pad rings of buffers NOT aliased with the live union region
  k_border<<<512, 256, 0, stream>>>(xf1, 68, 2, 64, 8);
  k_border<<<512, 256, 0, stream>>>(centerpad, 66, 1, 64, 2);
  k_border<<<512, 256, 0, stream>>>(nfpad, 66, 1, 64, 8);
  k_border<<<512, 256, 0, stream>>>(gatedpad, 66, 1, 256, 2);

  k_reorder_w2<<<2048, 256, 0, stream>>>(Wd, WdT, 1024);
  k_reorder_w2<<<512, 256, 0, stream>>>(Wc, WcT, 2048);
  k_reorder_wg<<<288, 256, 0, stream>>>(Wg, WgT);
  k_pad<<<dim3(64, 10), 256, 0, stream>>>(x, xf1, centerpad);
  k_corr<<<dim3(4, 4, 32), 256, 0, stream>>>(x, cpart);
  k_corr_combine<<<dim3(200, 4), 256, 0, stream>>>(cpart, corr, maxb);
  k_attn3<<<dim3(4, 4, 128), 256, 0, stream>>>(xf1, corr, maxb, nfpad);
  k_gate3<<<dim3(8, 64, 8), 256, 0, stream>>>(centerpad, nfpad, WgT, bg, gw);

  // xf1/corr/cpart are dead NOW -> safe to zero fg's pad ring (fg aliases them)
  k_border<<<512, 256, 0, stream>>>(fg, 66, 1, 128, batched ? 8 : 2);

  if (batched) {
    k_fg<<<dim3(4096, 4), 256, 0, stream>>>(centerpad, nfpad, gw, fg, 0);
    conv5<1024, 0><<<256, 512, 0, stream>>>(fg, WdT, bd, gatedpad, nullptr, 0, 1);
  } else {
    for (int pair = 0; pair < 4; ++pair) {
      k_fg<<<dim3(4096, 1), 256, 0, stream>>>(centerpad, nfpad, gw, fg, pair);
      conv5<1024, 0><<<64, 512, 0, stream>>>(
          fg, WdT + (size_t)pair * 512 * 9216, bd, gatedpad, nullptr, pair, 0);
    }
  }
  conv5<2048, 2><<<256, 512, 0, stream>>>(gatedpad, WcT, nullptr, nullptr, wcp, 0, 1);
  k_combine2<<<2048, 256, 0, stream>>>(wcp, bc, out);
}

// Round 13
// 772.384 us; speedup vs baseline: 1.1324x; 1.0183x over previous
//
#include <hip/hip_runtime.h>
#include <hip/hip_bf16.h>
#include <stdint.h>

typedef __attribute__((ext_vector_type(8))) short bf16x8;
typedef __attribute__((ext_vector_type(4))) float f32x4;
typedef __attribute__((ext_vector_type(2))) float f32x2;
typedef __attribute__((ext_vector_type(4))) int int4v;

#define DEVI static __device__ __forceinline__

DEVI unsigned short f2b(float f) {
  union { float f; unsigned u; } v; v.f = f;
  unsigned r = (v.u + 0x7FFFu + ((v.u >> 16) & 1u)) >> 16;
  return (unsigned short)r;
}
DEVI float b2f(unsigned short h) {
  union { unsigned u; float f; } v; v.u = ((unsigned)h) << 16;
  return v.f;
}
DEVI unsigned encf(float f) {
  union { float f; unsigned u; } v; v.f = f;
  return (v.u & 0x80000000u) ? ~v.u : (v.u | 0x80000000u);
}
DEVI float decf(unsigned u) {
  union { unsigned u; float f; } v;
  v.u = (u & 0x80000000u) ? (u & 0x7FFFFFFFu) : ~u;
  return v.f;
}
DEVI void gload16(const void* g, void* l) {
  __builtin_amdgcn_global_load_lds(
      (const __attribute__((address_space(1))) unsigned int*)g,
      (__attribute__((address_space(3))) unsigned int*)l, 16, 0, 0);
}

// ---------------- weight reorder: dst[r][cib][tap][ci32] bf16 <- src[r][ci][tap] f32
__global__ __launch_bounds__(256) void k_reorder_w2(const float* __restrict__ src,
                                                    unsigned short* __restrict__ dst,
                                                    int CI) {
  int r = blockIdx.x;
  int t = threadIdx.x;
  const float* s = src + (size_t)r * CI * 9;
  unsigned short* d = dst + (size_t)r * CI * 9;
  for (int ci0 = 0; ci0 < CI; ci0 += 256) {
    int ci = ci0 + t;
    float v[9];
#pragma unroll
    for (int k = 0; k < 9; k++) v[k] = s[(size_t)ci * 9 + k];
    unsigned short* db = d + (size_t)(ci >> 5) * 288 + (ci & 31);
#pragma unroll
    for (int k = 0; k < 9; k++) db[(size_t)k * 32] = f2b(v[k]);
  }
}

// WgT[po][tap][ciw32][chunk32] f32 <- Wg[po][ci][tap]  (ci = chunk*32 + ciw)
__global__ void k_reorder_wg(const float* __restrict__ src, float* __restrict__ dst) {
  int idx = blockIdx.x * 256 + threadIdx.x;  // total 73728
  int ci = idx & 1023;
  int rt = idx >> 10;
  int tap = rt % 9;
  int po = rt / 9;
  dst[(((size_t)po * 9 + tap) * 32 + (ci & 31)) * 32 + (ci >> 5)] =
      src[((size_t)po * 1024 + ci) * 9 + tap];
}

// ---------------- zero the pad ring of an NHWC buffer (replaces big memsets)
__global__ void k_border(unsigned short* __restrict__ p, int H, int wpad, int C8,
                         int nImg) {
  int inner = H - 2 * wpad;
  int borderPx = H * H - inner * inner;
  long total = (long)borderPx * C8 * nImg;
  int topN = wpad * H;
  for (long i = (long)blockIdx.x * 256 + threadIdx.x; i < total;
       i += (long)gridDim.x * 256) {
    int c = (int)(i % C8);
    long r2 = i / C8;
    int px = (int)(r2 % borderPx);
    int img = (int)(r2 / borderPx);
    int y, x;
    if (px < topN) {
      y = px / H; x = px % H;
    } else if (px < 2 * topN) {
      int q = px - topN; y = H - 1 - (q / H); x = q % H;
    } else {
      int q = px - 2 * topN;
      int row = q / (2 * wpad), cc = q % (2 * wpad);
      y = wpad + row;
      x = cc < wpad ? cc : H - 2 * wpad + cc;
    }
    *(int4v*)&p[((((size_t)img * H + y) * H + x) * C8 + c) * 8] = int4v{0, 0, 0, 0};
  }
}

// ---------------- pad/transpose: x NCHW f32 -> NHWC bf16
__global__ __launch_bounds__(256) void k_pad(const float* __restrict__ xin,
                                             unsigned short* __restrict__ xf1,
                                             unsigned short* __restrict__ cp) {
  __shared__ unsigned short lds[64 * 66];
  int t = threadIdx.x;
  int y = blockIdx.x;   // 0..63
  int fb = blockIdx.y;  // 0..9 = f*2+b
  int f = fb >> 1, b = fb & 1;
  const float* src = xin + (size_t)fb * 512 * 4096 + y * 64;
  unsigned short* base;
  if (f == 2) {
    base = cp + (((size_t)b * 66) + y + 1) * 66 * 512 + 512;
  } else {
    int fi = f < 2 ? f : f - 1;
    base = xf1 + (((size_t)(fi * 2 + b) * 68) + y + 2) * 68 * 512 + 2 * 512;
  }
  for (int c0 = 0; c0 < 512; c0 += 64) {
#pragma unroll
    for (int r = 0; r < 16; ++r) {
      int ci = r * 4 + (t >> 6);
      int xx = t & 63;
      lds[ci * 66 + xx] = f2b(src[(size_t)(c0 + ci) * 4096 + xx]);
    }
    __syncthreads();
    int xp = t >> 2;
    int cc = (t & 3) * 16;
    __align__(16) unsigned short vals[16];
#pragma unroll
    for (int i = 0; i < 16; i++) vals[i] = lds[(cc + i) * 66 + xp];
    unsigned short* dst = base + (size_t)xp * 512 + c0 + cc;
    *(int4v*)(dst) = *(const int4v*)(vals);
    *(int4v*)(dst + 8) = *(const int4v*)(vals + 8);
    __syncthreads();
  }
}

// ---------------- correlation partials (f32): corrpart[part][pair][b][25][64][64]
// channel pairs packed as float2 in LDS (stride-21 layout for both store+read)
__global__ __launch_bounds__(256) void k_corr(const float* __restrict__ xin,
                                              float* __restrict__ corrpart) {
  __shared__ f32x2 f1h2[420];  // [20][21] of channel-pair
  int t = threadIdx.x;
  int tx = t & 15, ty = t >> 4;
  int x0 = blockIdx.x * 16, y0 = blockIdx.y * 16;
  int z = blockIdx.z;
  int b = z & 1, pair = (z >> 1) & 3, part = z >> 3;
  int s = pair < 2 ? pair : pair + 1;
  const float* f2 = xin + ((size_t)(2 * 2 + b) * 512) * 4096;
  const float* f1 = xin + ((size_t)(s * 2 + b) * 512) * 4096;

  // slot t (always) and slot t+256 (t<144): r=k/20, c=k%20; LDS index r*21+c
  int r0 = t / 20, c0 = t - r0 * 20;
  int ls0 = r0 * 21 + c0;
  int gy0 = y0 + r0 - 2, gx0 = x0 + c0 - 2;
  bool val0 = ((unsigned)gy0 < 64u) && ((unsigned)gx0 < 64u);
  int go0 = gy0 * 64 + gx0;
  bool has1 = t < 144;
  int s1 = t + 256;
  int r1 = s1 / 20, c1 = s1 - r1 * 20;
  int ls1 = r1 * 21 + c1;
  int gy1 = y0 + r1 - 2, gx1 = x0 + c1 - 2;
  bool val1 = ((unsigned)gy1 < 64u) && ((unsigned)gx1 < 64u);
  int go1 = gy1 * 64 + gx1;

  float acc[25];
#pragma unroll
  for (int d = 0; d < 25; d++) acc[d] = 0.f;
  int y = y0 + ty, x = x0 + tx;
  for (int c = part * 128; c < part * 128 + 128; c += 2) {
    {
      float a0 = 0.f, b0v = 0.f;
      if (val0) {
        a0 = f1[(size_t)c * 4096 + go0];
        b0v = f1[(size_t)(c + 1) * 4096 + go0];
      }
      f1h2[ls0] = f32x2{a0, b0v};
      if (has1) {
        float a1 = 0.f, b1v = 0.f;
        if (val1) {
          a1 = f1[(size_t)c * 4096 + go1];
          b1v = f1[(size_t)(c + 1) * 4096 + go1];
        }
        f1h2[ls1] = f32x2{a1, b1v};
      }
    }
    float f2a = f2[(size_t)c * 4096 + y * 64 + x];
    float f2c = f2[(size_t)(c + 1) * 4096 + y * 64 + x];
    __syncthreads();
#pragma unroll
    for (int d = 0; d < 25; ++d) {
      int di = d / 5, dj = d % 5;
      f32x2 v = f1h2[(ty + di) * 21 + tx + dj];
      acc[d] += f2a * v[0] + f2c * v[1];
    }
    __syncthreads();
  }
  float* out = corrpart + ((size_t)((part * 4 + pair) * 2 + b) * 25) * 4096;
#pragma unroll
  for (int d = 0; d < 25; d++) out[(size_t)d * 4096 + y * 64 + x] = acc[d];
}

// ---------------- combine partials + global max per pair
__global__ __launch_bounds__(256) void k_corr_combine(const float* __restrict__ cpart,
                                                      float* __restrict__ corr,
                                                      unsigned* __restrict__ maxb) {
  const size_t PERPAIR = (size_t)2 * 25 * 4096;
  int pair = blockIdx.y;
  size_t i4 = ((size_t)blockIdx.x * 256 + threadIdx.x) * 4;
  f32x4 sacc = {0.f, 0.f, 0.f, 0.f};
#pragma unroll
  for (int p = 0; p < 4; p++)
    sacc += *(const f32x4*)(cpart + ((size_t)(p * 4 + pair)) * PERPAIR + i4);
  *(f32x4*)(corr + (size_t)pair * PERPAIR + i4) = sacc;
  float m = fmaxf(fmaxf(sacc[0], sacc[1]), fmaxf(sacc[2], sacc[3]));
#pragma unroll
  for (int off = 32; off; off >>= 1) m = fmaxf(m, __shfl_xor(m, off));
  __shared__ float wm[4];
  if ((threadIdx.x & 63) == 0) wm[threadIdx.x >> 6] = m;
  __syncthreads();
  if (threadIdx.x == 0) {
    float mm = fmaxf(fmaxf(wm[0], wm[1]), fmaxf(wm[2], wm[3]));
    atomicMax(maxb + pair, encf(mm));
  }
}

// ---------------- softmax + 5x5 gather from bf16 NHWC -> nfpad [pair][b][66][66][512]
__global__ __launch_bounds__(256) void k_attn3(const unsigned short* __restrict__ xf1,
                                               const float* __restrict__ corr,
                                               const unsigned* __restrict__ maxb,
                                               unsigned short* __restrict__ nfpad) {
  __shared__ unsigned short f1t[400 * 8];
  int t = threadIdx.x;
  int tx = t & 15, ty = t >> 4;
  int x0 = blockIdx.x * 16, y0 = blockIdx.y * 16;
  int z = blockIdx.z;
  int b = z & 1, pair = (z >> 1) & 3, cgh = z >> 3;
  const unsigned short* f1 = xf1 + ((size_t)(pair * 2 + b)) * 68 * 68 * 512;
  int y = y0 + ty, x = x0 + tx;
  const float* cr = corr + ((size_t)(pair * 2 + b)) * 25 * 4096 + y * 64 + x;

  int r0 = t / 20, c0 = t - r0 * 20;
  size_t go0 = ((size_t)(y0 + r0) * 68 + (x0 + c0)) * 512;
  bool has1 = t < 144;
  int k1 = t + 256;
  int r1 = k1 / 20, c1 = k1 - r1 * 20;
  size_t go1 = ((size_t)(y0 + r1) * 68 + (x0 + c1)) * 512;

  float p[25];
  float mx = -1e30f;
#pragma unroll
  for (int d = 0; d < 25; d++) {
    p[d] = cr[(size_t)d * 4096];
    mx = fmaxf(mx, p[d]);
  }
  float gs = 20.f / decf(maxb[pair]);
  float ss = 0.f;
#pragma unroll
  for (int d = 0; d < 25; d++) {
    p[d] = __expf((p[d] - mx) * gs);
    ss += p[d];
  }
  float inv = 1.f / ss;
#pragma unroll
  for (int d = 0; d < 25; d++) p[d] *= inv;

  for (int q = 0; q < 4; ++q) {
    int cg = cgh * 4 + q;
    *(int4v*)&f1t[t * 8] = *(const int4v*)&f1[go0 + cg * 8];
    if (has1) *(int4v*)&f1t[k1 * 8] = *(const int4v*)&f1[go1 + cg * 8];
    __syncthreads();
    float acc[8] = {0.f, 0.f, 0.f, 0.f, 0.f, 0.f, 0.f, 0.f};
#pragma unroll
    for (int d = 0; d < 25; d++) {
      bf16x8 v = *(const bf16x8*)&f1t[((ty + d / 5) * 20 + tx + d % 5) * 8];
      float pd = p[d];
#pragma unroll
      for (int e = 0; e < 8; e++) acc[e] += pd * b2f((unsigned short)v[e]);
    }
    __align__(16) unsigned short o[8];
#pragma unroll
    for (int e = 0; e < 8; e++) o[e] = f2b(acc[e]);
    *(int4v*)&nfpad[(((size_t)(pair * 2 + b) * 66 + (y + 1)) * 66 + (x + 1)) * 512 +
                    cg * 8] = *(const int4v*)o;
    __syncthreads();
  }
}

// ---------------- gate conv, coalesced weight reads via [po][tap][ciw][chunk] layout
__global__ __launch_bounds__(256) void k_gate3(const unsigned short* __restrict__ cp,
                                               const unsigned short* __restrict__ nfp,
                                               const float* __restrict__ wgt,
                                               const float* __restrict__ bg,
                                               float* __restrict__ gw) {
  int t = threadIdx.x;
  int z = blockIdx.z;
  int b = z & 1, pair = z >> 1;
  int y = blockIdx.y;
  int x = blockIdx.x * 8 + (t >> 5);
  int chunk = t & 31;
  int ci0 = chunk * 32;
  int half = ci0 >> 9;
  int ch0 = ci0 & 511;
  const unsigned short* src = half ? (nfp + ((size_t)(pair * 2 + b)) * 66 * 66 * 512)
                                   : (cp + ((size_t)b) * 66 * 66 * 512);
  const float* w0b = wgt + ((size_t)(pair * 2 + 0) * 9) * 1024;
  const float* w1b = wgt + ((size_t)(pair * 2 + 1) * 9) * 1024;
  float a0 = 0.f, a1 = 0.f;
  for (int tap = 0; tap < 9; ++tap) {
    int ky = tap / 3, kx = tap % 3;
    const unsigned short* ip = src + ((size_t)(y + ky) * 66 + (x + kx)) * 512 + ch0;
    const float* w0 = w0b + tap * 1024 + chunk;
    const float* w1 = w1b + tap * 1024 + chunk;
#pragma unroll
    for (int q = 0; q < 4; ++q) {
      bf16x8 v8 = *(const bf16x8*)(ip + q * 8);
#pragma unroll
      for (int e = 0; e < 8; e++) {
        float f = b2f((unsigned short)v8[e]);
        a0 += f * w0[(q * 8 + e) * 32];
        a1 += f * w1[(q * 8 + e) * 32];
      }
    }
  }
#pragma unroll
  for (int md = 1; md < 32; md <<= 1) {
    a0 += __shfl_xor(a0, md);
    a1 += __shfl_xor(a1, md);
  }
  if ((t & 31) == 0) {
    float g0 = 1.f / (1.f + __expf(-(a0 + bg[pair * 2 + 0])));
    float g1 = 1.f / (1.f + __expf(-(a1 + bg[pair * 2 + 1])));
    gw[(((size_t)(pair * 2 + b) * 2 + 0) * 64 + y) * 64 + x] = g0;
    gw[(((size_t)(pair * 2 + b) * 2 + 1) * 64 + y) * 64 + x] = g1;
  }
}

// ---------------- fg = [center*g0, nf*g1] -> fgp[pz][2][66][66][1024] bf16
__global__ __launch_bounds__(256) void k_fg(const unsigned short* __restrict__ cp,
                                            const unsigned short* __restrict__ nfp,
                                            const float* __restrict__ gw,
                                            unsigned short* __restrict__ fgp, int pairBase) {
  int pz = blockIdx.y;
  int pair = pairBase + pz;
  unsigned short* dstBase = fgp + (size_t)pz * 2 * 66 * 66 * 1024;
  size_t idx = (size_t)blockIdx.x * 256 + threadIdx.x;
  int chunk = (int)(idx & 127);
  size_t px = idx >> 7;
  int b = (int)(px >> 12), rem = (int)(px & 4095);
  int y = rem >> 6, x = rem & 63;
  int ci0 = chunk * 8;
  int half = ci0 >> 9;
  float g = gw[(((size_t)(pair * 2 + b) * 2 + half) * 64 + y) * 64 + x];
  const unsigned short* src = half ? (nfp + ((size_t)(pair * 2 + b)) * 66 * 66 * 512)
                                   : (cp + (size_t)b * 66 * 66 * 512);
  size_t poff = ((size_t)(y + 1) * 66 + (x + 1)) * 512 + (ci0 - half * 512);
  bf16x8 v = *(const bf16x8*)(src + poff);
  __align__(16) unsigned short o[8];
#pragma unroll
  for (int e = 0; e < 8; e++) o[e] = f2b(b2f((unsigned short)v[e]) * g);
  *(int4v*)(dstBase + ((size_t)(b * 66 + y + 1) * 66 + (x + 1)) * 1024 + ci0) =
      *(const int4v*)o;
}

// ---------------- 256x256x64 implicit-GEMM conv, 2-barrier schedule:
// R1 = all 24 ds_reads (issued early) overlapping quads Q00+Q10; full lgkm drain
// at R1 end -> block-wide "no reads from cur in flight" before any restage.
// R2 = all 8 restages (kt+2 -> cur) + Q11 + Q01 + counted vmcnt(8).
// MODE 0: Wd batched (multiz=1). MODE 2: Wc split-K/nz (multiz=2: nz=8, z=bid&7).
template <int CI, int MODE>
__global__ __launch_bounds__(512) void conv5(const unsigned short* __restrict__ inB,
                                             const unsigned short* __restrict__ WTb,
                                             const float* __restrict__ bias,
                                             unsigned short* __restrict__ outB,
                                             unsigned short* __restrict__ outP,
                                             int pairOfs, int multiz, int nz) {
  constexpr int K = 9 * CI;
  constexpr int KTOT = K / 64;
  __shared__ unsigned short As[2 * 2 * 8192];
  __shared__ unsigned short Bs[2 * 2 * 8192];

  int t = threadIdx.x;
  int bid = blockIdx.x;
  int z, m, n;
  if (multiz == 2) {
    z = bid & 7; m = (bid >> 3) & 1; n = bid >> 4;
  } else if (multiz == 1) {
    int xcd = bid & 7;
    z = xcd >> 1; m = xcd & 1; n = bid >> 3;
  } else {
    z = 0; m = bid & 1; n = bid >> 1;
  }
  const int KT = (MODE == 2) ? KTOT / nz : KTOT;
  const unsigned short* inPad = (MODE == 0) ? inB + (size_t)z * 2 * 66 * 66 * 1024 : inB;
  const unsigned short* WT = (MODE == 0) ? WTb + (size_t)z * 512 * 9216 : WTb;
  const int kt0 = (MODE == 2) ? z * KT : 0;
  const int ktEnd = kt0 + KT;
  int co0 = m * 256, n0 = n * 256;

  int rowS[2], kcS[2], linS[2];
  size_t bpix2[2][2];
#pragma unroll
  for (int rr = 0; rr < 2; rr++) {
    int idx2 = rr * 512 + t;
    rowS[rr] = idx2 >> 3;
    kcS[rr] = (idx2 & 7) ^ (rowS[rr] & 7);
    linS[rr] = idx2 * 8;
#pragma unroll
    for (int h = 0; h < 2; h++) {
      int ng = n0 + h * 128 + rowS[rr];
      int bb = ng >> 12, yy = (ng >> 6) & 63, xx = ng & 63;
      bpix2[h][rr] = (size_t)((bb * 66 + yy) * 66 + xx) * CI + (kcS[rr] & 3) * 8;
    }
  }

  f32x4 acc[8][4];
#pragma unroll
  for (int i = 0; i < 8; i++)
#pragma unroll
    for (int j = 0; j < 4; j++) acc[i][j] = f32x4{0.f, 0.f, 0.f, 0.f};

  int wid = t >> 6, l = t & 63;
  int wm = wid >> 2, wn = wid & 3;
  int lrow = l & 15, lk4 = l >> 4;

  auto stA = [&](int bufp, int h, int kt) {
#pragma unroll
    for (int rr = 0; rr < 2; rr++)
      gload16(WT + (size_t)(co0 + h * 128 + rowS[rr]) * K + kt * 64 + kcS[rr] * 8,
              &As[(bufp * 2 + h) * 8192 + linS[rr]]);
  };
  auto stB = [&](int bufp, int h, int kt) {
    int g0 = kt * 2, g1 = g0 + 1;
    int cib0 = g0 / 9, tap0 = g0 - cib0 * 9;
    int cib1 = g1 / 9, tap1 = g1 - cib1 * 9;
    int off0 = ((tap0 / 3) * 66 + tap0 % 3) * CI + cib0 * 32;
    int off1 = ((tap1 / 3) * 66 + tap1 % 3) * CI + cib1 * 32;
#pragma unroll
    for (int rr = 0; rr < 2; rr++)
      gload16(inPad + bpix2[h][rr] + ((kcS[rr] & 4) ? off1 : off0),
              &Bs[(bufp * 2 + h) * 8192 + linS[rr]]);
  };

  bf16x8 afr0[4][2], afr1[4][2], bfr0[2][2], bfr1[2][2];

#define RDA(DST, C, MH)                                                         \
  _Pragma("unroll") for (int ii = 0; ii < 4; ++ii) {                            \
    int row = (MH)*64 + ii * 16 + lrow;                                         \
    _Pragma("unroll") for (int kk = 0; kk < 2; ++kk) {                          \
      int pos = (kk * 4 + lk4) ^ (lrow & 7);                                    \
      DST[ii][kk] = *(const bf16x8*)&As[((C)*2 + wm) * 8192 + row * 64 + pos * 8]; \
    }                                                                           \
  }
#define RDB(DST, C, NH)                                                         \
  _Pragma("unroll") for (int j = 0; j < 2; ++j) {                               \
    int row = (wn & 1) * 64 + (NH)*32 + j * 16 + lrow;                          \
    _Pragma("unroll") for (int kk = 0; kk < 2; ++kk) {                          \
      int pos = (kk * 4 + lk4) ^ (lrow & 7);                                    \
      DST[j][kk] =                                                              \
          *(const bf16x8*)&Bs[((C)*2 + (wn >> 1)) * 8192 + row * 64 + pos * 8]; \
    }                                                                           \
  }
#define QUAD(AF, BF, MH, NH)                                                    \
  __builtin_amdgcn_s_setprio(1);                                                \
  _Pragma("unroll") for (int ii = 0; ii < 4; ++ii) {                            \
    _Pragma("unroll") for (int j = 0; j < 2; ++j) {                             \
      _Pragma("unroll") for (int kk = 0; kk < 2; ++kk) {                        \
        acc[(MH)*4 + ii][(NH)*2 + j] = __builtin_amdgcn_mfma_f32_16x16x32_bf16( \
            AF[ii][kk], BF[j][kk], acc[(MH)*4 + ii][(NH)*2 + j], 0, 0, 0);      \
      }                                                                         \
    }                                                                           \
  }                                                                             \
  __builtin_amdgcn_s_setprio(0);
#define DRAIN_LGKM asm volatile("s_waitcnt lgkmcnt(0)" ::: "memory");

  // prologue: stage kt0 -> buf0, kt0+1 -> buf1 (8+8 loads); wait kt0, barrier
  {
    int b0 = kt0 & 1, b1 = b0 ^ 1;
    stA(b0, 0, kt0); stA(b0, 1, kt0); stB(b0, 0, kt0); stB(b0, 1, kt0);
    stA(b1, 0, kt0 + 1); stA(b1, 1, kt0 + 1); stB(b1, 0, kt0 + 1); stB(b1, 1, kt0 + 1);
    asm volatile("s_waitcnt vmcnt(8)" ::: "memory");
    __builtin_amdgcn_s_barrier();
  }

  for (int kt = kt0; kt < ktEnd; ++kt) {
    int cur = kt & 1;
    const bool pf = (kt + 2 < ktEnd);
    // R1: issue ALL 24 ds_reads early, overlap with Q00 + Q10 (compiler emits
    // counted lgkm waits); full drain at region end = all reads from cur done.
    RDA(afr0, cur, 0);
    RDB(bfr0, cur, 0);
    RDB(bfr1, cur, 1);
    QUAD(afr0, bfr0, 0, 0)
    RDA(afr1, cur, 1);
    QUAD(afr1, bfr0, 1, 0)
    DRAIN_LGKM
    __builtin_amdgcn_s_barrier();
    // R2: restage all of kt+2 into cur (safe: block-wide drain above), then
    // remaining 2 quads from registers; counted vmcnt retires kt+1's loads.
    if (pf) {
      stA(cur, 0, kt + 2); stA(cur, 1, kt + 2);
      stB(cur, 0, kt + 2); stB(cur, 1, kt + 2);
    }
    QUAD(afr1, bfr1, 1, 1)
    QUAD(afr0, bfr1, 0, 1)
    if (pf) {
      asm volatile("s_waitcnt vmcnt(8)" ::: "memory");
    } else {
      asm volatile("s_waitcnt vmcnt(0)" ::: "memory");
    }
    __builtin_amdgcn_s_barrier();
  }
#undef RDA
#undef RDB
#undef QUAD
#undef DRAIN_LGKM

#pragma unroll
  for (int i = 0; i < 8; i++) {
#pragma unroll
    for (int j = 0; j < 4; j++) {
      int col = wn * 64 + j * 16 + lrow;
      int ng = n0 + col;
      int bb = ng >> 12, yy = (ng >> 6) & 63, xx = ng & 63;
#pragma unroll
      for (int r = 0; r < 4; r++) {
        int row = wm * 128 + i * 16 + lk4 * 4 + r;
        int co = co0 + row;
        if (MODE == 0) {
          int zc = (z + pairOfs) * 512 + co;
          float v = acc[i][j][r] + bias[zc];
          v = v > 0.f ? v : 0.f;
          outB[((size_t)(bb * 66 + yy + 1) * 66 + (xx + 1)) * 2048 + zc] = f2b(v);
        } else {
          outP[((size_t)(z * 512 + co) << 13) + ng] = f2b(acc[i][j][r]);
        }
      }
    }
  }
}

// ---------------- combine split-K bf16 partials: out = relu(sum + bias), f32 NCHW
__global__ __launch_bounds__(256) void k_combine2(const unsigned short* __restrict__ p,
                                                  const float* __restrict__ bc,
                                                  float* __restrict__ out, int nz) {
  size_t i8 = ((size_t)blockIdx.x * 256 + threadIdx.x) * 8;  // over 512*8192
  int co = (int)(i8 >> 13);
  int ng = (int)(i8 & 8191);
  float s[8] = {0.f, 0.f, 0.f, 0.f, 0.f, 0.f, 0.f, 0.f};
  for (int zz = 0; zz < nz; zz++) {
    bf16x8 v = *(const bf16x8*)&p[((size_t)(zz * 512 + co) << 13) + ng];
#pragma unroll
    for (int e = 0; e < 8; e++) s[e] += b2f((unsigned short)v[e]);
  }
  float bb = bc[co];
  int batch = ng >> 12, rem = ng & 4095;
  float* o = out + (((size_t)(batch * 512 + co)) << 12) + rem;
#pragma unroll
  for (int e = 0; e < 8; e++) {
    float q = s[e] + bb;
    o[e] = q > 0.f ? q : 0.f;
  }
}

extern "C" void kernel_launch(void* const* d_in, const int* in_sizes, int n_in,
                              void* d_out, int out_size, void* d_ws, size_t ws_size,
                              hipStream_t stream) {
  const float* x = (const float*)d_in[0];
  const float* Wg = (const float*)d_in[1];
  const float* bg = (const float*)d_in[2];
  const float* Wd = (const float*)d_in[3];
  const float* bd = (const float*)d_in[4];
  const float* Wc = (const float*)d_in[5];
  const float* bc = (const float*)d_in[6];
  float* out = (float*)d_out;

  char* ws = (char*)d_ws;
  size_t off = 0;
  auto alloc = [&](size_t bytes) {
    void* p = ws + off;
    off = (off + bytes + 255) & ~(size_t)255;
    return p;
  };
  const size_t SZ_WDT = (size_t)2048 * 9216 * 2;
  const size_t SZ_WCT = (size_t)512 * 18432 * 2;
  const size_t SZ_WGT = (size_t)4 * 2 * 9 * 1024 * 4;
  const size_t SZ_CP = (size_t)2 * 66 * 66 * 512 * 2;
  const size_t SZ_NF = (size_t)4 * 2 * 66 * 66 * 512 * 2;
  const size_t SZ_GT = (size_t)2 * 66 * 66 * 2048 * 2;
  const size_t SZ_GW = (size_t)4 * 2 * 2 * 4096 * 4;
  const size_t SZ_XF1 = (size_t)4 * 2 * 68 * 68 * 512 * 2;
  const size_t SZ_CORR = (size_t)4 * 2 * 25 * 4096 * 4;
  const size_t SZ_FG1 = (size_t)2 * 66 * 66 * 1024 * 2;
  const size_t SZ_FG4 = SZ_FG1 * 4;

  unsigned short* WdT = (unsigned short*)alloc(SZ_WDT);
  unsigned short* WcT = (unsigned short*)alloc(SZ_WCT);
  float* WgT = (float*)alloc(SZ_WGT);
  unsigned short* centerpad = (unsigned short*)alloc(SZ_CP);
  unsigned short* nfpad = (unsigned short*)alloc(SZ_NF);
  unsigned short* gatedpad = (unsigned short*)alloc(SZ_GT);
  float* gw = (float*)alloc(SZ_GW);
  unsigned* maxb = (unsigned*)alloc(256);

  // union region: phase1 {xf1, corr, cpart} -> phase2 {fg} -> phase3 {wcp}
  size_t unionOff = off;
  unsigned short* xf1 = (unsigned short*)(ws + unionOff);
  size_t o2 = unionOff + ((SZ_XF1 + 255) & ~(size_t)255);
  float* corr = (float*)(ws + o2);
  float* cpart = (float*)(ws + o2 + ((SZ_CORR + 255) & ~(size_t)255));
  unsigned short* fg = (unsigned short*)(ws + unionOff);
  unsigned short* wcp = (unsigned short*)(ws + unionOff);
  bool batched = ws_size >= unionOff + SZ_FG4;

  hipMemsetAsync(maxb, 0, 64, stream);

  // zero pad rings of buffers NOT aliased with the live union region
  k_border<<<512, 256, 0, stream>>>(xf1, 68, 2, 64, 8);
  k_border<<<512, 256, 0, stream>>>(centerpad, 66, 1, 64, 2);
  k_border<<<512, 256, 0, stream>>>(nfpad, 66, 1, 64, 8);
  k_border<<<512, 256, 0, stream>>>(gatedpad, 66, 1, 256, 2);

  k_reorder_w2<<<2048, 256, 0, stream>>>(Wd, WdT, 1024);
  k_reorder_w2<<<512, 256, 0, stream>>>(Wc, WcT, 2048);
  k_reorder_wg<<<288, 256, 0, stream>>>(Wg, WgT);
  k_pad<<<dim3(64, 10), 256, 0, stream>>>(x, xf1, centerpad);
  k_corr<<<dim3(4, 4, 32), 256, 0, stream>>>(x, cpart);
  k_corr_combine<<<dim3(200, 4), 256, 0, stream>>>(cpart, corr, maxb);
  k_attn3<<<dim3(4, 4, 128), 256, 0, stream>>>(xf1, corr, maxb, nfpad);
  k_gate3<<<dim3(8, 64, 8), 256, 0, stream>>>(centerpad, nfpad, WgT, bg, gw);

  // xf1/corr/cpart are dead NOW -> safe to zero fg's pad ring (fg aliases them)
  k_border<<<512, 256, 0, stream>>>(fg, 66, 1, 128, batched ? 8 : 2);

  if (batched) {
    k_fg<<<dim3(4096, 4), 256, 0, stream>>>(centerpad, nfpad, gw, fg, 0);
    conv5<1024, 0><<<256, 512, 0, stream>>>(fg, WdT, bd, gatedpad, nullptr, 0, 1, 1);
    conv5<2048, 2><<<512, 512, 0, stream>>>(gatedpad, WcT, nullptr, nullptr, wcp, 0, 2, 8);
    k_combine2<<<2048, 256, 0, stream>>>(wcp, bc, out, 8);
  } else {
    for (int pair = 0; pair < 4; ++pair) {
      k_fg<<<dim3(4096, 1), 256, 0, stream>>>(centerpad, nfpad, gw, fg, pair);
      conv5<1024, 0><<<64, 512, 0, stream>>>(
          fg, WdT + (size_t)pair * 512 * 9216, bd, gatedpad, nullptr, pair, 0, 1);
    }
    conv5<2048, 2><<<256, 512, 0, stream>>>(gatedpad, WcT, nullptr, nullptr, wcp, 0, 1, 4);
    k_combine2<<<2048, 256, 0, stream>>>(wcp, bc, out, 4);
  }
}

// Round 16
// 752.453 us; speedup vs baseline: 1.1624x; 1.0265x over previous
//
#include <hip/hip_runtime.h>
#include <hip/hip_bf16.h>
#include <stdint.h>

typedef __attribute__((ext_vector_type(8))) short bf16x8;
typedef __attribute__((ext_vector_type(4))) float f32x4;
typedef __attribute__((ext_vector_type(2))) float f32x2;
typedef __attribute__((ext_vector_type(4))) int int4v;

#define DEVI static __device__ __forceinline__

DEVI unsigned short f2b(float f) {
  union { float f; unsigned u; } v; v.f = f;
  unsigned r = (v.u + 0x7FFFu + ((v.u >> 16) & 1u)) >> 16;
  return (unsigned short)r;
}
DEVI float b2f(unsigned short h) {
  union { unsigned u; float f; } v; v.u = ((unsigned)h) << 16;
  return v.f;
}
DEVI unsigned encf(float f) {
  union { float f; unsigned u; } v; v.f = f;
  return (v.u & 0x80000000u) ? ~v.u : (v.u | 0x80000000u);
}
DEVI float decf(unsigned u) {
  union { unsigned u; float f; } v;
  v.u = (u & 0x80000000u) ? (u & 0x7FFFFFFFu) : ~u;
  return v.f;
}
DEVI void gload16(const void* g, void* l) {
  __builtin_amdgcn_global_load_lds(
      (const __attribute__((address_space(1))) unsigned int*)g,
      (__attribute__((address_space(3))) unsigned int*)l, 16, 0, 0);
}

// ---------------- weight reorder: dst[r][cib][tap][ci32] bf16 <- src[r][ci][tap] f32
__global__ __launch_bounds__(256) void k_reorder_w2(const float* __restrict__ src,
                                                    unsigned short* __restrict__ dst,
                                                    int CI) {
  int r = blockIdx.x;
  int t = threadIdx.x;
  const float* s = src + (size_t)r * CI * 9;
  unsigned short* d = dst + (size_t)r * CI * 9;
  for (int ci0 = 0; ci0 < CI; ci0 += 256) {
    int ci = ci0 + t;
    float v[9];
#pragma unroll
    for (int k = 0; k < 9; k++) v[k] = s[(size_t)ci * 9 + k];
    unsigned short* db = d + (size_t)(ci >> 5) * 288 + (ci & 31);
#pragma unroll
    for (int k = 0; k < 9; k++) db[(size_t)k * 32] = f2b(v[k]);
  }
}

// WgT[po][tap][ciw32][chunk32] f32 <- Wg[po][ci][tap]  (ci = chunk*32 + ciw)
__global__ void k_reorder_wg(const float* __restrict__ src, float* __restrict__ dst) {
  int idx = blockIdx.x * 256 + threadIdx.x;  // total 73728
  int ci = idx & 1023;
  int rt = idx >> 10;
  int tap = rt % 9;
  int po = rt / 9;
  dst[(((size_t)po * 9 + tap) * 32 + (ci & 31)) * 32 + (ci >> 5)] =
      src[((size_t)po * 1024 + ci) * 9 + tap];
}

// ---------------- zero the pad ring of an NHWC buffer (replaces big memsets)
__global__ void k_border(unsigned short* __restrict__ p, int H, int wpad, int C8,
                         int nImg) {
  int inner = H - 2 * wpad;
  int borderPx = H * H - inner * inner;
  long total = (long)borderPx * C8 * nImg;
  int topN = wpad * H;
  for (long i = (long)blockIdx.x * 256 + threadIdx.x; i < total;
       i += (long)gridDim.x * 256) {
    int c = (int)(i % C8);
    long r2 = i / C8;
    int px = (int)(r2 % borderPx);
    int img = (int)(r2 / borderPx);
    int y, x;
    if (px < topN) {
      y = px / H; x = px % H;
    } else if (px < 2 * topN) {
      int q = px - topN; y = H - 1 - (q / H); x = q % H;
    } else {
      int q = px - 2 * topN;
      int row = q / (2 * wpad), cc = q % (2 * wpad);
      y = wpad + row;
      x = cc < wpad ? cc : H - 2 * wpad + cc;
    }
    *(int4v*)&p[((((size_t)img * H + y) * H + x) * C8 + c) * 8] = int4v{0, 0, 0, 0};
  }
}

// ---------------- pad/transpose: x NCHW f32 -> NHWC bf16
__global__ __launch_bounds__(256) void k_pad(const float* __restrict__ xin,
                                             unsigned short* __restrict__ xf1,
                                             unsigned short* __restrict__ cp) {
  __shared__ unsigned short lds[64 * 66];
  int t = threadIdx.x;
  int y = blockIdx.x;   // 0..63
  int fb = blockIdx.y;  // 0..9 = f*2+b
  int f = fb >> 1, b = fb & 1;
  const float* src = xin + (size_t)fb * 512 * 4096 + y * 64;
  unsigned short* base;
  if (f == 2) {
    base = cp + (((size_t)b * 66) + y + 1) * 66 * 512 + 512;
  } else {
    int fi = f < 2 ? f : f - 1;
    base = xf1 + (((size_t)(fi * 2 + b) * 68) + y + 2) * 68 * 512 + 2 * 512;
  }
  for (int c0 = 0; c0 < 512; c0 += 64) {
#pragma unroll
    for (int r = 0; r < 16; ++r) {
      int ci = r * 4 + (t >> 6);
      int xx = t & 63;
      lds[ci * 66 + xx] = f2b(src[(size_t)(c0 + ci) * 4096 + xx]);
    }
    __syncthreads();
    int xp = t >> 2;
    int cc = (t & 3) * 16;
    __align__(16) unsigned short vals[16];
#pragma unroll
    for (int i = 0; i < 16; i++) vals[i] = lds[(cc + i) * 66 + xp];
    unsigned short* dst = base + (size_t)xp * 512 + c0 + cc;
    *(int4v*)(dst) = *(const int4v*)(vals);
    *(int4v*)(dst + 8) = *(const int4v*)(vals + 8);
    __syncthreads();
  }
}

// ---------------- correlation partials (f32): corrpart[part][pair][b][25][64][64]
__global__ __launch_bounds__(256) void k_corr(const float* __restrict__ xin,
                                              float* __restrict__ corrpart) {
  __shared__ f32x2 f1h2[420];  // [20][21] of channel-pair
  int t = threadIdx.x;
  int tx = t & 15, ty = t >> 4;
  int x0 = blockIdx.x * 16, y0 = blockIdx.y * 16;
  int z = blockIdx.z;
  int b = z & 1, pair = (z >> 1) & 3, part = z >> 3;
  int s = pair < 2 ? pair : pair + 1;
  const float* f2 = xin + ((size_t)(2 * 2 + b) * 512) * 4096;
  const float* f1 = xin + ((size_t)(s * 2 + b) * 512) * 4096;

  int r0 = t / 20, c0 = t - r0 * 20;
  int ls0 = r0 * 21 + c0;
  int gy0 = y0 + r0 - 2, gx0 = x0 + c0 - 2;
  bool val0 = ((unsigned)gy0 < 64u) && ((unsigned)gx0 < 64u);
  int go0 = gy0 * 64 + gx0;
  bool has1 = t < 144;
  int s1 = t + 256;
  int r1 = s1 / 20, c1 = s1 - r1 * 20;
  int ls1 = r1 * 21 + c1;
  int gy1 = y0 + r1 - 2, gx1 = x0 + c1 - 2;
  bool val1 = ((unsigned)gy1 < 64u) && ((unsigned)gx1 < 64u);
  int go1 = gy1 * 64 + gx1;

  float acc[25];
#pragma unroll
  for (int d = 0; d < 25; d++) acc[d] = 0.f;
  int y = y0 + ty, x = x0 + tx;
  for (int c = part * 128; c < part * 128 + 128; c += 2) {
    {
      float a0 = 0.f, b0v = 0.f;
      if (val0) {
        a0 = f1[(size_t)c * 4096 + go0];
        b0v = f1[(size_t)(c + 1) * 4096 + go0];
      }
      f1h2[ls0] = f32x2{a0, b0v};
      if (has1) {
        float a1 = 0.f, b1v = 0.f;
        if (val1) {
          a1 = f1[(size_t)c * 4096 + go1];
          b1v = f1[(size_t)(c + 1) * 4096 + go1];
        }
        f1h2[ls1] = f32x2{a1, b1v};
      }
    }
    float f2a = f2[(size_t)c * 4096 + y * 64 + x];
    float f2c = f2[(size_t)(c + 1) * 4096 + y * 64 + x];
    __syncthreads();
#pragma unroll
    for (int d = 0; d < 25; ++d) {
      int di = d / 5, dj = d % 5;
      f32x2 v = f1h2[(ty + di) * 21 + tx + dj];
      acc[d] += f2a * v[0] + f2c * v[1];
    }
    __syncthreads();
  }
  float* out = corrpart + ((size_t)((part * 4 + pair) * 2 + b) * 25) * 4096;
#pragma unroll
  for (int d = 0; d < 25; d++) out[(size_t)d * 4096 + y * 64 + x] = acc[d];
}

// ---------------- combine partials + global max per pair
__global__ __launch_bounds__(256) void k_corr_combine(const float* __restrict__ cpart,
                                                      float* __restrict__ corr,
                                                      unsigned* __restrict__ maxb) {
  const size_t PERPAIR = (size_t)2 * 25 * 4096;
  int pair = blockIdx.y;
  size_t i4 = ((size_t)blockIdx.x * 256 + threadIdx.x) * 4;
  f32x4 sacc = {0.f, 0.f, 0.f, 0.f};
#pragma unroll
  for (int p = 0; p < 4; p++)
    sacc += *(const f32x4*)(cpart + ((size_t)(p * 4 + pair)) * PERPAIR + i4);
  *(f32x4*)(corr + (size_t)pair * PERPAIR + i4) = sacc;
  float m = fmaxf(fmaxf(sacc[0], sacc[1]), fmaxf(sacc[2], sacc[3]));
#pragma unroll
  for (int off = 32; off; off >>= 1) m = fmaxf(m, __shfl_xor(m, off));
  __shared__ float wm[4];
  if ((threadIdx.x & 63) == 0) wm[threadIdx.x >> 6] = m;
  __syncthreads();
  if (threadIdx.x == 0) {
    float mm = fmaxf(fmaxf(wm[0], wm[1]), fmaxf(wm[2], wm[3]));
    atomicMax(maxb + pair, encf(mm));
  }
}

// ---------------- softmax + 5x5 gather from bf16 NHWC -> nfpad [pair][b][66][66][512]
__global__ __launch_bounds__(256) void k_attn3(const unsigned short* __restrict__ xf1,
                                               const float* __restrict__ corr,
                                               const unsigned* __restrict__ maxb,
                                               unsigned short* __restrict__ nfpad) {
  __shared__ unsigned short f1t[400 * 8];
  int t = threadIdx.x;
  int tx = t & 15, ty = t >> 4;
  int x0 = blockIdx.x * 16, y0 = blockIdx.y * 16;
  int z = blockIdx.z;
  int b = z & 1, pair = (z >> 1) & 3, cgh = z >> 3;
  const unsigned short* f1 = xf1 + ((size_t)(pair * 2 + b)) * 68 * 68 * 512;
  int y = y0 + ty, x = x0 + tx;
  const float* cr = corr + ((size_t)(pair * 2 + b)) * 25 * 4096 + y * 64 + x;

  int r0 = t / 20, c0 = t - r0 * 20;
  size_t go0 = ((size_t)(y0 + r0) * 68 + (x0 + c0)) * 512;
  bool has1 = t < 144;
  int k1 = t + 256;
  int r1 = k1 / 20, c1 = k1 - r1 * 20;
  size_t go1 = ((size_t)(y0 + r1) * 68 + (x0 + c1)) * 512;

  float p[25];
  float mx = -1e30f;
#pragma unroll
  for (int d = 0; d < 25; d++) {
    p[d] = cr[(size_t)d * 4096];
    mx = fmaxf(mx, p[d]);
  }
  float gs = 20.f / decf(maxb[pair]);
  float ss = 0.f;
#pragma unroll
  for (int d = 0; d < 25; d++) {
    p[d] = __expf((p[d] - mx) * gs);
    ss += p[d];
  }
  float inv = 1.f / ss;
#pragma unroll
  for (int d = 0; d < 25; d++) p[d] *= inv;

  for (int q = 0; q < 4; ++q) {
    int cg = cgh * 4 + q;
    *(int4v*)&f1t[t * 8] = *(const int4v*)&f1[go0 + cg * 8];
    if (has1) *(int4v*)&f1t[k1 * 8] = *(const int4v*)&f1[go1 + cg * 8];
    __syncthreads();
    float acc[8] = {0.f, 0.f, 0.f, 0.f, 0.f, 0.f, 0.f, 0.f};
#pragma unroll
    for (int d = 0; d < 25; d++) {
      bf16x8 v = *(const bf16x8*)&f1t[((ty + d / 5) * 20 + tx + d % 5) * 8];
      float pd = p[d];
#pragma unroll
      for (int e = 0; e < 8; e++) acc[e] += pd * b2f((unsigned short)v[e]);
    }
    __align__(16) unsigned short o[8];
#pragma unroll
    for (int e = 0; e < 8; e++) o[e] = f2b(acc[e]);
    *(int4v*)&nfpad[(((size_t)(pair * 2 + b) * 66 + (y + 1)) * 66 + (x + 1)) * 512 +
                    cg * 8] = *(const int4v*)o;
    __syncthreads();
  }
}

// ---------------- gate conv, coalesced weight reads via [po][tap][ciw][chunk] layout
__global__ __launch_bounds__(256) void k_gate3(const unsigned short* __restrict__ cp,
                                               const unsigned short* __restrict__ nfp,
                                               const float* __restrict__ wgt,
                                               const float* __restrict__ bg,
                                               float* __restrict__ gw) {
  int t = threadIdx.x;
  int z = blockIdx.z;
  int b = z & 1, pair = z >> 1;
  int y = blockIdx.y;
  int x = blockIdx.x * 8 + (t >> 5);
  int chunk = t & 31;
  int ci0 = chunk * 32;
  int half = ci0 >> 9;
  int ch0 = ci0 & 511;
  const unsigned short* src = half ? (nfp + ((size_t)(pair * 2 + b)) * 66 * 66 * 512)
                                   : (cp + ((size_t)b) * 66 * 66 * 512);
  const float* w0b = wgt + ((size_t)(pair * 2 + 0) * 9) * 1024;
  const float* w1b = wgt + ((size_t)(pair * 2 + 1) * 9) * 1024;
  float a0 = 0.f, a1 = 0.f;
  for (int tap = 0; tap < 9; ++tap) {
    int ky = tap / 3, kx = tap % 3;
    const unsigned short* ip = src + ((size_t)(y + ky) * 66 + (x + kx)) * 512 + ch0;
    const float* w0 = w0b + tap * 1024 + chunk;
    const float* w1 = w1b + tap * 1024 + chunk;
#pragma unroll
    for (int q = 0; q < 4; ++q) {
      bf16x8 v8 = *(const bf16x8*)(ip + q * 8);
#pragma unroll
      for (int e = 0; e < 8; e++) {
        float f = b2f((unsigned short)v8[e]);
        a0 += f * w0[(q * 8 + e) * 32];
        a1 += f * w1[(q * 8 + e) * 32];
      }
    }
  }
#pragma unroll
  for (int md = 1; md < 32; md <<= 1) {
    a0 += __shfl_xor(a0, md);
    a1 += __shfl_xor(a1, md);
  }
  if ((t & 31) == 0) {
    float g0 = 1.f / (1.f + __expf(-(a0 + bg[pair * 2 + 0])));
    float g1 = 1.f / (1.f + __expf(-(a1 + bg[pair * 2 + 1])));
    gw[(((size_t)(pair * 2 + b) * 2 + 0) * 64 + y) * 64 + x] = g0;
    gw[(((size_t)(pair * 2 + b) * 2 + 1) * 64 + y) * 64 + x] = g1;
  }
}

// ---------------- fg = [center*g0, nf*g1] -> fgp[pz][2][66][66][1024] bf16
__global__ __launch_bounds__(256) void k_fg(const unsigned short* __restrict__ cp,
                                            const unsigned short* __restrict__ nfp,
                                            const float* __restrict__ gw,
                                            unsigned short* __restrict__ fgp, int pairBase) {
  int pz = blockIdx.y;
  int pair = pairBase + pz;
  unsigned short* dstBase = fgp + (size_t)pz * 2 * 66 * 66 * 1024;
  size_t idx = (size_t)blockIdx.x * 256 + threadIdx.x;
  int chunk = (int)(idx & 127);
  size_t px = idx >> 7;
  int b = (int)(px >> 12), rem = (int)(px & 4095);
  int y = rem >> 6, x = rem & 63;
  int ci0 = chunk * 8;
  int half = ci0 >> 9;
  float g = gw[(((size_t)(pair * 2 + b) * 2 + half) * 64 + y) * 64 + x];
  const unsigned short* src = half ? (nfp + ((size_t)(pair * 2 + b)) * 66 * 66 * 512)
                                   : (cp + (size_t)b * 66 * 66 * 512);
  size_t poff = ((size_t)(y + 1) * 66 + (x + 1)) * 512 + (ci0 - half * 512);
  bf16x8 v = *(const bf16x8*)(src + poff);
  __align__(16) unsigned short o[8];
#pragma unroll
  for (int e = 0; e < 8; e++) o[e] = f2b(b2f((unsigned short)v[e]) * g);
  *(int4v*)(dstBase + ((size_t)(b * 66 + y + 1) * 66 + (x + 1)) * 1024 + ci0) =
      *(const int4v*)o;
}

// ---------------- 256x256x64 implicit-GEMM conv, r11-verified 3-region schedule.
// LDS half selection is PER-WAVE (A: wm, B: wn>>1) -- NOT per quad-arg. Liveness:
// A's reads (RDA afr0+afr1, both halves wm) all complete in R1 -> restage A in R2.
// B's reads (RDB bfr0 in R1, bfr1 in R2 -- both touch the wave's half wn>>1)
// complete by R2's drain -> restage B in R3 ONLY. vmcnt(8) once per tile.
// MODE 0: Wd batched (multiz=1). MODE 2: Wc split-K/nz (multiz=2: nz=8, z=bid&7).
template <int CI, int MODE>
__global__ __launch_bounds__(512) void conv5(const unsigned short* __restrict__ inB,
                                             const unsigned short* __restrict__ WTb,
                                             const float* __restrict__ bias,
                                             unsigned short* __restrict__ outB,
                                             unsigned short* __restrict__ outP,
                                             int pairOfs, int multiz, int nz) {
  constexpr int K = 9 * CI;
  constexpr int KTOT = K / 64;
  __shared__ unsigned short As[2 * 2 * 8192];
  __shared__ unsigned short Bs[2 * 2 * 8192];

  int t = threadIdx.x;
  int bid = blockIdx.x;
  int z, m, n;
  if (multiz == 2) {
    z = bid & 7; m = (bid >> 3) & 1; n = bid >> 4;
  } else if (multiz == 1) {
    int xcd = bid & 7;
    z = xcd >> 1; m = xcd & 1; n = bid >> 3;
  } else {
    z = 0; m = bid & 1; n = bid >> 1;
  }
  const int KT = (MODE == 2) ? KTOT / nz : KTOT;
  const unsigned short* inPad = (MODE == 0) ? inB + (size_t)z * 2 * 66 * 66 * 1024 : inB;
  const unsigned short* WT = (MODE == 0) ? WTb + (size_t)z * 512 * 9216 : WTb;
  const int kt0 = (MODE == 2) ? z * KT : 0;
  const int ktEnd = kt0 + KT;
  int co0 = m * 256, n0 = n * 256;

  int rowS[2], kcS[2], linS[2];
  size_t bpix2[2][2];
#pragma unroll
  for (int rr = 0; rr < 2; rr++) {
    int idx2 = rr * 512 + t;
    rowS[rr] = idx2 >> 3;
    kcS[rr] = (idx2 & 7) ^ (rowS[rr] & 7);
    linS[rr] = idx2 * 8;
#pragma unroll
    for (int h = 0; h < 2; h++) {
      int ng = n0 + h * 128 + rowS[rr];
      int bb = ng >> 12, yy = (ng >> 6) & 63, xx = ng & 63;
      bpix2[h][rr] = (size_t)((bb * 66 + yy) * 66 + xx) * CI + (kcS[rr] & 3) * 8;
    }
  }

  f32x4 acc[8][4];
#pragma unroll
  for (int i = 0; i < 8; i++)
#pragma unroll
    for (int j = 0; j < 4; j++) acc[i][j] = f32x4{0.f, 0.f, 0.f, 0.f};

  int wid = t >> 6, l = t & 63;
  int wm = wid >> 2, wn = wid & 3;
  int lrow = l & 15, lk4 = l >> 4;

  auto stA = [&](int bufp, int h, int kt) {
#pragma unroll
    for (int rr = 0; rr < 2; rr++)
      gload16(WT + (size_t)(co0 + h * 128 + rowS[rr]) * K + kt * 64 + kcS[rr] * 8,
              &As[(bufp * 2 + h) * 8192 + linS[rr]]);
  };
  auto stB = [&](int bufp, int h, int kt) {
    int g0 = kt * 2, g1 = g0 + 1;
    int cib0 = g0 / 9, tap0 = g0 - cib0 * 9;
    int cib1 = g1 / 9, tap1 = g1 - cib1 * 9;
    int off0 = ((tap0 / 3) * 66 + tap0 % 3) * CI + cib0 * 32;
    int off1 = ((tap1 / 3) * 66 + tap1 % 3) * CI + cib1 * 32;
#pragma unroll
    for (int rr = 0; rr < 2; rr++)
      gload16(inPad + bpix2[h][rr] + ((kcS[rr] & 4) ? off1 : off0),
              &Bs[(bufp * 2 + h) * 8192 + linS[rr]]);
  };

  bf16x8 afr0[4][2], afr1[4][2], bfr0[2][2], bfr1[2][2];

#define RDA(DST, C, MH)                                                         \
  _Pragma("unroll") for (int ii = 0; ii < 4; ++ii) {                            \
    int row = (MH)*64 + ii * 16 + lrow;                                         \
    _Pragma("unroll") for (int kk = 0; kk < 2; ++kk) {                          \
      int pos = (kk * 4 + lk4) ^ (lrow & 7);                                    \
      DST[ii][kk] = *(const bf16x8*)&As[((C)*2 + wm) * 8192 + row * 64 + pos * 8]; \
    }                                                                           \
  }
#define RDB(DST, C, NH)                                                         \
  _Pragma("unroll") for (int j = 0; j < 2; ++j) {                               \
    int row = (wn & 1) * 64 + (NH)*32 + j * 16 + lrow;                          \
    _Pragma("unroll") for (int kk = 0; kk < 2; ++kk) {                          \
      int pos = (kk * 4 + lk4) ^ (lrow & 7);                                    \
      DST[j][kk] =                                                              \
          *(const bf16x8*)&Bs[((C)*2 + (wn >> 1)) * 8192 + row * 64 + pos * 8]; \
    }                                                                           \
  }
#define QUAD(AF, BF, MH, NH)                                                    \
  __builtin_amdgcn_s_setprio(1);                                                \
  _Pragma("unroll") for (int ii = 0; ii < 4; ++ii) {                            \
    _Pragma("unroll") for (int j = 0; j < 2; ++j) {                             \
      _Pragma("unroll") for (int kk = 0; kk < 2; ++kk) {                        \
        acc[(MH)*4 + ii][(NH)*2 + j] = __builtin_amdgcn_mfma_f32_16x16x32_bf16( \
            AF[ii][kk], BF[j][kk], acc[(MH)*4 + ii][(NH)*2 + j], 0, 0, 0);      \
      }                                                                         \
    }                                                                           \
  }                                                                             \
  __builtin_amdgcn_s_setprio(0);
#define DRAIN_LGKM asm volatile("s_waitcnt lgkmcnt(0)" ::: "memory");

  // prologue: stage kt0 -> buf0, kt0+1 -> buf1 (8+8 loads); wait kt0, barrier
  {
    int b0 = kt0 & 1, b1 = b0 ^ 1;
    stA(b0, 0, kt0); stA(b0, 1, kt0); stB(b0, 0, kt0); stB(b0, 1, kt0);
    stA(b1, 0, kt0 + 1); stA(b1, 1, kt0 + 1); stB(b1, 0, kt0 + 1); stB(b1, 1, kt0 + 1);
    asm volatile("s_waitcnt vmcnt(8)" ::: "memory");
    __builtin_amdgcn_s_barrier();
  }

  for (int kt = kt0; kt < ktEnd; ++kt) {
    int cur = kt & 1;
    const bool pf = (kt + 2 < ktEnd);
    // R1: A reads (both subtiles of wave's half) + B-subtile0 reads overlap
    // quads Q00+Q10; full drain at region end -> A buffer dead block-wide.
    RDA(afr0, cur, 0);
    RDB(bfr0, cur, 0);
    QUAD(afr0, bfr0, 0, 0)
    RDA(afr1, cur, 1);
    QUAD(afr1, bfr0, 1, 0)
    DRAIN_LGKM
    __builtin_amdgcn_s_barrier();
    // R2: restage A (kt+2) only -- B is still being read here (bfr1 touches
    // the wave's B half). Quad Q11; drain -> B buffer dead after barrier.
    if (pf) { stA(cur, 0, kt + 2); stA(cur, 1, kt + 2); }
    RDB(bfr1, cur, 1);
    QUAD(afr1, bfr1, 1, 1)
    DRAIN_LGKM
    __builtin_amdgcn_s_barrier();
    // R3: restage B (kt+2); quad Q01; counted vmcnt (kt+1's 8 loads retired).
    if (pf) { stB(cur, 0, kt + 2); stB(cur, 1, kt + 2); }
    QUAD(afr0, bfr1, 0, 1)
    if (pf) {
      asm volatile("s_waitcnt vmcnt(8)" ::: "memory");
    } else {
      asm volatile("s_waitcnt vmcnt(0)" ::: "memory");
    }
    __builtin_amdgcn_s_barrier();
  }
#undef RDA
#undef RDB
#undef QUAD
#undef DRAIN_LGKM

#pragma unroll
  for (int i = 0; i < 8; i++) {
#pragma unroll
    for (int j = 0; j < 4; j++) {
      int col = wn * 64 + j * 16 + lrow;
      int ng = n0 + col;
      int bb = ng >> 12, yy = (ng >> 6) & 63, xx = ng & 63;
#pragma unroll
      for (int r = 0; r < 4; r++) {
        int row = wm * 128 + i * 16 + lk4 * 4 + r;
        int co = co0 + row;
        if (MODE == 0) {
          int zc = (z + pairOfs) * 512 + co;
          float v = acc[i][j][r] + bias[zc];
          v = v > 0.f ? v : 0.f;
          outB[((size_t)(bb * 66 + yy + 1) * 66 + (xx + 1)) * 2048 + zc] = f2b(v);
        } else {
          outP[((size_t)(z * 512 + co) << 13) + ng] = f2b(acc[i][j][r]);
        }
      }
    }
  }
}

// ---------------- combine split-K bf16 partials: out = relu(sum + bias), f32 NCHW
__global__ __launch_bounds__(256) void k_combine2(const unsigned short* __restrict__ p,
                                                  const float* __restrict__ bc,
                                                  float* __restrict__ out, int nz) {
  size_t i8 = ((size_t)blockIdx.x * 256 + threadIdx.x) * 8;  // over 512*8192
  int co = (int)(i8 >> 13);
  int ng = (int)(i8 & 8191);
  float s[8] = {0.f, 0.f, 0.f, 0.f, 0.f, 0.f, 0.f, 0.f};
  for (int zz = 0; zz < nz; zz++) {
    bf16x8 v = *(const bf16x8*)&p[((size_t)(zz * 512 + co) << 13) + ng];
#pragma unroll
    for (int e = 0; e < 8; e++) s[e] += b2f((unsigned short)v[e]);
  }
  float bb = bc[co];
  int batch = ng >> 12, rem = ng & 4095;
  float* o = out + (((size_t)(batch * 512 + co)) << 12) + rem;
#pragma unroll
  for (int e = 0; e < 8; e++) {
    float q = s[e] + bb;
    o[e] = q > 0.f ? q : 0.f;
  }
}

extern "C" void kernel_launch(void* const* d_in, const int* in_sizes, int n_in,
                              void* d_out, int out_size, void* d_ws, size_t ws_size,
                              hipStream_t stream) {
  const float* x = (const float*)d_in[0];
  const float* Wg = (const float*)d_in[1];
  const float* bg = (const float*)d_in[2];
  const float* Wd = (const float*)d_in[3];
  const float* bd = (const float*)d_in[4];
  const float* Wc = (const float*)d_in[5];
  const float* bc = (const float*)d_in[6];
  float* out = (float*)d_out;

  char* ws = (char*)d_ws;
  size_t off = 0;
  auto alloc = [&](size_t bytes) {
    void* p = ws + off;
    off = (off + bytes + 255) & ~(size_t)255;
    return p;
  };
  const size_t SZ_WDT = (size_t)2048 * 9216 * 2;
  const size_t SZ_WCT = (size_t)512 * 18432 * 2;
  const size_t SZ_WGT = (size_t)4 * 2 * 9 * 1024 * 4;
  const size_t SZ_CP = (size_t)2 * 66 * 66 * 512 * 2;
  const size_t SZ_NF = (size_t)4 * 2 * 66 * 66 * 512 * 2;
  const size_t SZ_GT = (size_t)2 * 66 * 66 * 2048 * 2;
  const size_t SZ_GW = (size_t)4 * 2 * 2 * 4096 * 4;
  const size_t SZ_XF1 = (size_t)4 * 2 * 68 * 68 * 512 * 2;
  const size_t SZ_CORR = (size_t)4 * 2 * 25 * 4096 * 4;
  const size_t SZ_FG1 = (size_t)2 * 66 * 66 * 1024 * 2;
  const size_t SZ_FG4 = SZ_FG1 * 4;

  unsigned short* WdT = (unsigned short*)alloc(SZ_WDT);
  unsigned short* WcT = (unsigned short*)alloc(SZ_WCT);
  float* WgT = (float*)alloc(SZ_WGT);
  unsigned short* centerpad = (unsigned short*)alloc(SZ_CP);
  unsigned short* nfpad = (unsigned short*)alloc(SZ_NF);
  unsigned short* gatedpad = (unsigned short*)alloc(SZ_GT);
  float* gw = (float*)alloc(SZ_GW);
  unsigned* maxb = (unsigned*)alloc(256);

  // union region: phase1 {xf1, corr, cpart} -> phase2 {fg} -> phase3 {wcp}
  size_t unionOff = off;
  unsigned short* xf1 = (unsigned short*)(ws + unionOff);
  size_t o2 = unionOff + ((SZ_XF1 + 255) & ~(size_t)255);
  float* corr = (float*)(ws + o2);
  float* cpart = (float*)(ws + o2 + ((SZ_CORR + 255) & ~(size_t)255));
  unsigned short* fg = (unsigned short*)(ws + unionOff);
  unsigned short* wcp = (unsigned short*)(ws + unionOff);
  bool batched = ws_size >= unionOff + SZ_FG4;

  hipMemsetAsync(maxb, 0, 64, stream);

  // zero pad rings of buffers NOT aliased with the live union region
  k_border<<<512, 256, 0, stream>>>(xf1, 68, 2, 64, 8);
  k_border<<<512, 256, 0, stream>>>(centerpad, 66, 1, 64, 2);
  k_border<<<512, 256, 0, stream>>>(nfpad, 66, 1, 64, 8);
  k_border<<<512, 256, 0, stream>>>(gatedpad, 66, 1, 256, 2);

  k_reorder_w2<<<2048, 256, 0, stream>>>(Wd, WdT, 1024);
  k_reorder_w2<<<512, 256, 0, stream>>>(Wc, WcT, 2048);
  k_reorder_wg<<<288, 256, 0, stream>>>(Wg, WgT);
  k_pad<<<dim3(64, 10), 256, 0, stream>>>(x, xf1, centerpad);
  k_corr<<<dim3(4, 4, 32), 256, 0, stream>>>(x, cpart);
  k_corr_combine<<<dim3(200, 4), 256, 0, stream>>>(cpart, corr, maxb);
  k_attn3<<<dim3(4, 4, 128), 256, 0, stream>>>(xf1, corr, maxb, nfpad);
  k_gate3<<<dim3(8, 64, 8), 256, 0, stream>>>(centerpad, nfpad, WgT, bg, gw);

  // xf1/corr/cpart are dead NOW -> safe to zero fg's pad ring (fg aliases them)
  k_border<<<512, 256, 0, stream>>>(fg, 66, 1, 128, batched ? 8 : 2);

  if (batched) {
    k_fg<<<dim3(4096, 4), 256, 0, stream>>>(centerpad, nfpad, gw, fg, 0);
    conv5<1024, 0><<<256, 512, 0, stream>>>(fg, WdT, bd, gatedpad, nullptr, 0, 1, 1);
    conv5<2048, 2><<<512, 512, 0, stream>>>(gatedpad, WcT, nullptr, nullptr, wcp, 0, 2, 8);
    k_combine2<<<2048, 256, 0, stream>>>(wcp, bc, out, 8);
  } else {
    for (int pair = 0; pair < 4; ++pair) {
      k_fg<<<dim3(4096, 1), 256, 0, stream>>>(centerpad, nfpad, gw, fg, pair);
      conv5<1024, 0><<<64, 512, 0, stream>>>(
          fg, WdT + (size_t)pair * 512 * 9216, bd, gatedpad, nullptr, pair, 0, 1);
    }
    conv5<2048, 2><<<256, 512, 0, stream>>>(gatedpad, WcT, nullptr, nullptr, wcp, 0, 1, 4);
    k_combine2<<<2048, 256, 0, stream>>>(wcp, bc, out, 4);
  }
}